// Round 1
// baseline (1914.714 us; speedup 1.0000x reference)
//
#include <hip/hip_runtime.h>
#include <math.h>

#define PI_F 3.14159274101257324f   // float(np.pi)

// ---------------- workspace layout (float offsets) ----------------
static const size_t OFF_FC    = 0;                    // row-FFT complex out [B*C*256][129]*2 ; later reused as ph_sp
static const size_t OFF_MLOG  = 3170304;              // [B,C,256,129]
static const size_t OFF_PH    = 4755456;              // [B,C,256,129]
static const size_t OFF_MSP   = 6340608;              // [B,C,256,256]
static const size_t OFF_RSUM  = 9486336;              // [B,C,32]
static const size_t OFF_RCNT  = OFF_RSUM + 1536;      // [32]
static const size_t OFF_AS1   = OFF_RCNT + 32;        // [B,C,8]
static const size_t OFF_AS2   = OFF_AS1 + 384;        // [B,C,8]
static const size_t OFF_ACNT  = OFF_AS2 + 384;        // [8]
static const size_t OFF_MPOOL = OFF_ACNT + 8;         // [B,64]
static const size_t OFF_PPOOL = OFF_MPOOL + 1024;     // [B,32]
static const size_t OFF_RF    = OFF_PPOOL + 512;      // [B,32]
static const size_t OFF_PAR   = OFF_RF + 512;         // 512 folded BN params
static const size_t OFF_W2TM  = OFF_PAR + 512;        // 36864 transposed mag w2
static const size_t OFF_W2TP  = OFF_W2TM + 36864;     // 9216 transposed ph w2
// param sub-offsets: sm1 0, tm1 64, sm2 128, tm2 192, sp1 256, tp1 288, sp2 320, tp2 352,
//                    sr1 384, tr1 416, sr2 448, tr2 480

__device__ __forceinline__ float fix_nan(float v, float pinf, float ninf) {
  if (isnan(v)) return 0.f;
  if (isinf(v)) return v > 0.f ? pinf : ninf;
  return v;
}

// ---------------- prep: fold BN, transpose conv2 weights ----------------
__device__ __forceinline__ void fold_bn(const float* bn, int C, int c, float cb,
                                        float* s, float* t) {
  float g = bn[c], b = bn[C + c], m = bn[2 * C + c], v = bn[3 * C + c];
  float sc = g / sqrtf(v + 1e-5f);
  *s = sc;
  *t = b + (cb - m) * sc;
}

__global__ __launch_bounds__(256) void prep_kernel(
    const float* __restrict__ mw2, const float* __restrict__ pw2,
    const float* __restrict__ mb1, const float* __restrict__ mbn1,
    const float* __restrict__ mb2, const float* __restrict__ mbn2,
    const float* __restrict__ pb1, const float* __restrict__ pbn1,
    const float* __restrict__ pb2, const float* __restrict__ pbn2,
    const float* __restrict__ rb1, const float* __restrict__ rbn1,
    const float* __restrict__ rb2, const float* __restrict__ rbn2,
    float* __restrict__ par, float* __restrict__ w2tm, float* __restrict__ w2tp) {
  int idx = blockIdx.x * 256 + threadIdx.x;
  if (idx < 36864) {
    int cik = idx >> 6, oc = idx & 63;
    int ci = cik / 9, k = cik % 9;
    w2tm[idx] = mw2[(oc * 64 + ci) * 9 + k];
  } else if (idx < 46080) {
    int i = idx - 36864;
    int cik = i >> 5, oc = i & 31;
    int ci = cik / 9, k = cik % 9;
    w2tp[i] = pw2[(oc * 32 + ci) * 9 + k];
  } else if (idx < 46336) {
    int i = idx - 46080;  // 0..255
    float s, t;
    if (i < 64)       { fold_bn(mbn1, 64, i, mb1[i], &s, &t);          par[i] = s;       par[64 + i] = t; }
    else if (i < 128) { int c = i - 64;  fold_bn(mbn2, 64, c, mb2[c], &s, &t); par[128 + c] = s; par[192 + c] = t; }
    else if (i < 160) { int c = i - 128; fold_bn(pbn1, 32, c, pb1[c], &s, &t); par[256 + c] = s; par[288 + c] = t; }
    else if (i < 192) { int c = i - 160; fold_bn(pbn2, 32, c, pb2[c], &s, &t); par[320 + c] = s; par[352 + c] = t; }
    else if (i < 224) { int c = i - 192; fold_bn(rbn1, 32, c, rb1[c], &s, &t); par[384 + c] = s; par[416 + c] = t; }
    else              { int c = i - 224; fold_bn(rbn2, 32, c, rb2[c], &s, &t); par[448 + c] = s; par[480 + c] = t; }
  }
}

// ---------------- row rFFT (along W): x[.,256] -> complex [.,129] ----------------
__global__ __launch_bounds__(256) void row_fft(const float* __restrict__ x,
                                               float* __restrict__ Fc) {
  const int blk = blockIdx.x;  // (b*3+c)*256 + y   (12288 blocks)
  const int tid = threadIdx.x;
  __shared__ float xr[256];
  __shared__ float2 tw[256];
  float v = x[(size_t)blk * 256 + tid];
  xr[tid] = fminf(fmaxf(v, -10.f), 10.f);
  float sn, cs;
  sincosf((float)(6.283185307179586 / 256.0) * (float)tid, &sn, &cs);
  tw[tid] = make_float2(cs, sn);
  __syncthreads();
  if (tid < 129) {
    float ar = 0.f, ai = 0.f;
    int t = 0;
#pragma unroll 4
    for (int w = 0; w < 256; ++w) {
      float xv = xr[w];
      float2 tt = tw[t];
      ar = fmaf(xv, tt.x, ar);
      ai = fmaf(xv, tt.y, ai);
      t = (t + tid) & 255;
    }
    float2* o = (float2*)Fc;
    o[(size_t)blk * 129 + tid] = make_float2(ar, -ai);
  }
}

// ---------------- column DFT (along H) + mag/phase + radial/azimuth stats ----------------
__global__ __launch_bounds__(256) void col_fft_stats(
    const float* __restrict__ Fc, float* __restrict__ mlog, float* __restrict__ ph,
    float* __restrict__ rsum, float* __restrict__ rcnt, float* __restrict__ as1,
    float* __restrict__ as2, float* __restrict__ acnt) {
  const int k = blockIdx.x, c = blockIdx.y, b = blockIdx.z;
  const int bc = b * 3 + c;
  const int tid = threadIdx.x;  // = output row j
  __shared__ float2 col[256];
  __shared__ float2 tw[256];
  __shared__ float l_rs[32], l_rc[32];
  __shared__ float l_s1[8], l_s2[8], l_ac[8];
  if (tid < 32) { l_rs[tid] = 0.f; l_rc[tid] = 0.f; }
  if (tid < 8)  { l_s1[tid] = 0.f; l_s2[tid] = 0.f; l_ac[tid] = 0.f; }
  const float2* fc = (const float2*)Fc;
  col[tid] = fc[((size_t)bc * 256 + tid) * 129 + k];
  float sn, cs;
  sincosf((float)(6.283185307179586 / 256.0) * (float)tid, &sn, &cs);
  tw[tid] = make_float2(cs, sn);
  __syncthreads();
  float gr = 0.f, gi = 0.f;
  int t = 0;
#pragma unroll 4
  for (int h = 0; h < 256; ++h) {
    float2 v = col[h];
    float2 w = tw[t];
    gr = fmaf(v.x, w.x, gr);
    gr = fmaf(v.y, w.y, gr);
    gi = fmaf(v.y, w.x, gi);
    gi = fmaf(v.x, -w.y, gi);
    t = (t + tid) & 255;
  }
  float mag = sqrtf(gr * gr + gi * gi);
  mag = fminf(fmaxf(mag, 1e-8f), 1e6f);
  float ml = fminf(fmaxf(log1pf(mag), -20.f), 20.f);
  float p = fminf(fmaxf(atan2f(gi, gr) / PI_F, -1.f), 1.f);
  mlog[((size_t)bc * 256 + tid) * 129 + k] = ml;
  ph[((size_t)bc * 256 + tid) * 129 + k] = p;
  // bins (bit-exact fp32 replication of the reference index math)
  float fy = (float)(tid < 128 ? tid : tid - 256) * (1.0f / 256.0f);
  float fx = (float)k * (1.0f / 256.0f);
  float rad = sqrtf(fx * fx + fy * fy);
  float denom = sqrtf(0.5f) + 1e-8f;
  int rb = (int)((rad / denom) * 31.0f);
  rb = rb < 0 ? 0 : (rb > 31 ? 31 : rb);
  float ang = atan2f(fy, fx + 1e-8f);
  int ab = (int)((ang + PI_F) / (2.0f * PI_F) * 8.0f);
  ab = ab < 0 ? 0 : (ab > 7 ? 7 : ab);
  atomicAdd(&l_rs[rb], mag);
  atomicAdd(&l_s1[ab], mag);
  atomicAdd(&l_s2[ab], mag * mag);
  if (bc == 0) {
    atomicAdd(&l_rc[rb], 1.0f);
    atomicAdd(&l_ac[ab], 1.0f);
  }
  __syncthreads();
  if (tid < 32) {
    atomicAdd(&rsum[bc * 32 + tid], l_rs[tid]);
    if (bc == 0) atomicAdd(&rcnt[tid], l_rc[tid]);
  } else if (tid < 40) {
    int a = tid - 32;
    atomicAdd(&as1[bc * 8 + a], l_s1[a]);
    atomicAdd(&as2[bc * 8 + a], l_s2[a]);
    if (bc == 0) atomicAdd(&acnt[a], l_ac[a]);
  }
}

// ---------------- bilinear W-upsample 129 -> 256 (H identity), both arrays ----------------
__global__ __launch_bounds__(256) void upsample2(const float* __restrict__ mlog,
                                                 const float* __restrict__ ph,
                                                 float* __restrict__ msp,
                                                 float* __restrict__ psp) {
  int idx = blockIdx.x * 256 + threadIdx.x;  // < 3145728
  if (idx >= 3145728) return;
  int xx = idx & 255;
  int row = idx >> 8;  // (b*3+c)*256 + y
  float src = ((float)xx + 0.5f) * (129.0f / 256.0f) - 0.5f;
  float fl = floorf(src);
  float w = src - fl;
  int x0 = (int)fl;
  int x1 = x0 + 1;
  x1 = x1 > 128 ? 128 : x1;
  x0 = x0 < 0 ? 0 : x0;
  const float* rm = mlog + (size_t)row * 129;
  const float* rp = ph + (size_t)row * 129;
  msp[idx] = rm[x0] * (1.f - w) + rm[x1] * w;
  psp[idx] = rp[x0] * (1.f - w) + rp[x1] * w;
}

// ---------------- fused conv1+BN+ReLU -> conv2+BN+ReLU -> global mean pool ----------------
// tile 16x16 outputs; thread = (2x2 spatial quad) x (C2/4 output channels)
template <int C2, int ICG>
__global__ __launch_bounds__(256) void conv_branch(
    const float* __restrict__ inp, const float* __restrict__ w1,
    const float* __restrict__ w2t, const float* __restrict__ s1,
    const float* __restrict__ t1, const float* __restrict__ s2,
    const float* __restrict__ t2, float* __restrict__ pool) {
  constexpr int OCP = C2 / 4;
  constexpr int NG = C2 / ICG;
  constexpr int W2G = ICG * 9 * C2;
  constexpr int POOLSZ = 256 * OCP;
  constexpr int USZ = (W2G > POOLSZ) ? W2G : POOLSZ;

  __shared__ float s_in[3][20][20];
  __shared__ float s_f1[ICG][18][18];
  __shared__ __align__(16) float s_u[USZ];
  __shared__ float s_w1[C2 * 27];
  __shared__ float s_sc1[C2], s_sh1[C2];

  const int tid = threadIdx.x;
  const int b = blockIdx.z;
  const int tx0 = blockIdx.x * 16, ty0 = blockIdx.y * 16;
  const int q = tid & 63, ocg = tid >> 6;
  const int lx = (q & 7) * 2, ly = (q >> 3) * 2;

  for (int idx = tid; idx < 1200; idx += 256) {
    int c = idx / 400, r = idx % 400, iy = r / 20, ix = r % 20;
    int gy = ty0 - 2 + iy, gx = tx0 - 2 + ix;
    float v = 0.f;
    if ((unsigned)gy < 256u && (unsigned)gx < 256u)
      v = inp[(((size_t)b * 3 + c) * 256 + gy) * 256 + gx];
    s_in[c][iy][ix] = v;
  }
  for (int idx = tid; idx < C2 * 27; idx += 256) s_w1[idx] = w1[idx];
  if (tid < C2) { s_sc1[tid] = s1[tid]; s_sh1[tid] = t1[tid]; }

  float acc[OCP * 4];
#pragma unroll
  for (int i = 0; i < OCP * 4; ++i) acc[i] = 0.f;

  for (int g = 0; g < NG; ++g) {
    __syncthreads();  // protects s_u / s_f1 from previous iteration readers
    for (int idx = tid; idx < W2G; idx += 256) s_u[idx] = w2t[g * W2G + idx];
    // conv1 + BN + ReLU over 18x18 halo region for this input-channel group.
    // Positions outside the image are ZERO (conv2's SAME padding pads feat1).
    for (int idx = tid; idx < ICG * 324; idx += 256) {
      int ci = idx / 324, r = idx % 324, fy = r / 18, fx = r % 18;
      int c2 = g * ICG + ci;
      int gy = ty0 - 1 + fy, gx = tx0 - 1 + fx;
      float v = 0.f;
      if ((unsigned)gy < 256u && (unsigned)gx < 256u) {
        float a = 0.f;
#pragma unroll
        for (int ic = 0; ic < 3; ++ic)
#pragma unroll
          for (int ky = 0; ky < 3; ++ky)
#pragma unroll
            for (int kx = 0; kx < 3; ++kx)
              a = fmaf(s_in[ic][fy + ky][fx + kx],
                       s_w1[c2 * 27 + ic * 9 + ky * 3 + kx], a);
        v = fmaxf(fmaf(a, s_sc1[c2], s_sh1[c2]), 0.f);
      }
      s_f1[ci][fy][fx] = v;
    }
    __syncthreads();
    // conv2 accumulation
    for (int ci = 0; ci < ICG; ++ci) {
#pragma unroll
      for (int k = 0; k < 9; ++k) {
        const int ky = k / 3, kx = k % 3;
        float f00 = s_f1[ci][ly + ky][lx + kx];
        float f01 = s_f1[ci][ly + ky][lx + kx + 1];
        float f10 = s_f1[ci][ly + ky + 1][lx + kx];
        float f11 = s_f1[ci][ly + ky + 1][lx + kx + 1];
        const float4* wrow = (const float4*)&s_u[(ci * 9 + k) * C2 + ocg * OCP];
#pragma unroll
        for (int j4 = 0; j4 < OCP / 4; ++j4) {
          float4 w = wrow[j4];
          float* a = &acc[j4 * 16];
          a[0] = fmaf(f00, w.x, a[0]);  a[1] = fmaf(f01, w.x, a[1]);
          a[2] = fmaf(f10, w.x, a[2]);  a[3] = fmaf(f11, w.x, a[3]);
          a[4] = fmaf(f00, w.y, a[4]);  a[5] = fmaf(f01, w.y, a[5]);
          a[6] = fmaf(f10, w.y, a[6]);  a[7] = fmaf(f11, w.y, a[7]);
          a[8] = fmaf(f00, w.z, a[8]);  a[9] = fmaf(f01, w.z, a[9]);
          a[10] = fmaf(f10, w.z, a[10]); a[11] = fmaf(f11, w.z, a[11]);
          a[12] = fmaf(f00, w.w, a[12]); a[13] = fmaf(f01, w.w, a[13]);
          a[14] = fmaf(f10, w.w, a[14]); a[15] = fmaf(f11, w.w, a[15]);
        }
      }
    }
  }
  __syncthreads();
  // epilogue: BN+ReLU then per-block pool partial
#pragma unroll
  for (int j = 0; j < OCP; ++j) {
    int oc = ocg * OCP + j;
    float sc = s2[oc], sh = t2[oc];
    float v = fmaxf(fmaf(acc[j * 4 + 0], sc, sh), 0.f) +
              fmaxf(fmaf(acc[j * 4 + 1], sc, sh), 0.f) +
              fmaxf(fmaf(acc[j * 4 + 2], sc, sh), 0.f) +
              fmaxf(fmaf(acc[j * 4 + 3], sc, sh), 0.f);
    s_u[tid * OCP + j] = v;
  }
  __syncthreads();
  if (tid < C2) {
    int og = tid / OCP, jj = tid % OCP;
    float s = 0.f;
    for (int qq = 0; qq < 64; ++qq) s += s_u[(og * 64 + qq) * OCP + jj];
    atomicAdd(&pool[b * C2 + tid], s);
  }
}

// ---------------- radial 1d conv branch ----------------
__global__ __launch_bounds__(128) void radial_conv(
    const float* __restrict__ rsum, const float* __restrict__ rcnt,
    const float* __restrict__ rw1, const float* __restrict__ rw2,
    const float* __restrict__ sr1, const float* __restrict__ tr1,
    const float* __restrict__ sr2, const float* __restrict__ tr2,
    float* __restrict__ rf) {
  int b = blockIdx.x, t = threadIdx.x;
  __shared__ float rad[3][32];
  __shared__ float f1[32][32];
  __shared__ float f2[32][32];
  if (t < 96) {
    int c = t / 32, i = t % 32;
    float cnt = fmaxf(rcnt[i], 1.0f);
    float v = rsum[(b * 3 + c) * 32 + i] / cnt;
    rad[c][i] = fminf(fmaxf(v, 0.f), 1e6f);
  }
  __syncthreads();
  for (int idx = t; idx < 1024; idx += 128) {
    int oc = idx >> 5, i = idx & 31;
    float a = 0.f;
    for (int c = 0; c < 3; ++c)
#pragma unroll
      for (int d = 0; d < 3; ++d) {
        int ii = i + d - 1;
        if (ii >= 0 && ii < 32) a = fmaf(rad[c][ii], rw1[(oc * 3 + c) * 3 + d], a);
      }
    f1[oc][i] = fmaxf(fmaf(a, sr1[oc], tr1[oc]), 0.f);
  }
  __syncthreads();
  for (int idx = t; idx < 1024; idx += 128) {
    int oc = idx >> 5, i = idx & 31;
    float a = 0.f;
    for (int c = 0; c < 32; ++c)
#pragma unroll
      for (int d = 0; d < 3; ++d) {
        int ii = i + d - 1;
        if (ii >= 0 && ii < 32) a = fmaf(f1[c][ii], rw2[(oc * 32 + c) * 3 + d], a);
      }
    f2[oc][i] = fmaxf(fmaf(a, sr2[oc], tr2[oc]), 0.f);
  }
  __syncthreads();
  if (t < 32) {
    float s = 0.f;
    for (int i = 0; i < 32; ++i) s += f2[t][i];
    rf[b * 32 + t] = s * (1.0f / 32.0f);
  }
}

// ---------------- final: comb assembly, linear, layernorm, relu, linear ----------------
__global__ __launch_bounds__(256) void final_mlp(
    const float* __restrict__ mpool, const float* __restrict__ ppool,
    const float* __restrict__ rf, const float* __restrict__ as1,
    const float* __restrict__ as2, const float* __restrict__ acnt,
    const float* __restrict__ lw1, const float* __restrict__ lb1,
    const float* __restrict__ lng, const float* __restrict__ lnb,
    const float* __restrict__ lw2, const float* __restrict__ lb2,
    float* __restrict__ out) {
  int b = blockIdx.x, t = threadIdx.x;
  __shared__ float comb[176];
  __shared__ float red[256];
  __shared__ float hrelu[256];
  __shared__ float s_mu, s_var;
  if (t < 64) comb[t] = fix_nan(mpool[b * 64 + t] * (1.0f / 65536.0f), 1e4f, -1e4f);
  else if (t < 96) comb[t] = fix_nan(ppool[b * 32 + t - 64] * (1.0f / 65536.0f), 1e4f, -1e4f);
  else if (t < 128) comb[t] = fix_nan(rf[b * 32 + t - 96], 1e4f, -1e4f);
  else if (t < 176) {
    int j = t - 128;
    int a = j / 6, r = j % 6, m = r / 3, c = r % 3;
    float cnt = acnt[a];
    float v = 0.f;  // empty sector -> NaN -> nan_to_num -> 0
    if (cnt > 0.f) {
      float s1v = as1[(b * 3 + c) * 8 + a], s2v = as2[(b * 3 + c) * 8 + a];
      float mean = s1v / cnt;
      if (m == 0)
        v = mean;
      else {
        float var = (s2v - cnt * mean * mean) / fmaxf(cnt - 1.f, 1.f);
        v = sqrtf(fmaxf(var, 0.f));
      }
    }
    comb[t] = fix_nan(v, 1e4f, -1e4f);
  }
  __syncthreads();
  float h = lb1[t];
  const float* wr = lw1 + t * 176;
#pragma unroll 8
  for (int j = 0; j < 176; ++j) h = fmaf(comb[j], wr[j], h);
  red[t] = h;
  __syncthreads();
  for (int s = 128; s > 0; s >>= 1) {
    if (t < s) red[t] += red[t + s];
    __syncthreads();
  }
  if (t == 0) s_mu = red[0] * (1.0f / 256.0f);
  __syncthreads();
  float mu = s_mu;
  float d = h - mu;
  red[t] = d * d;
  __syncthreads();
  for (int s = 128; s > 0; s >>= 1) {
    if (t < s) red[t] += red[t + s];
    __syncthreads();
  }
  if (t == 0) s_var = red[0] * (1.0f / 256.0f);
  __syncthreads();
  float hn = d / sqrtf(s_var + 1e-5f) * lng[t] + lnb[t];
  hrelu[t] = fmaxf(hn, 0.f);
  __syncthreads();
  if (t < 128) {
    float o = lb2[t];
    const float* w2r = lw2 + t * 256;
#pragma unroll 8
    for (int j = 0; j < 256; ++j) o = fmaf(hrelu[j], w2r[j], o);
    o = fminf(fmaxf(o, -100.f), 100.f);
    out[b * 128 + t] = fix_nan(o, 100.f, -100.f);
  }
}

// ---------------- host launcher ----------------
extern "C" void kernel_launch(void* const* d_in, const int* in_sizes, int n_in,
                              void* d_out, int out_size, void* d_ws, size_t ws_size,
                              hipStream_t stream) {
  const float* x    = (const float*)d_in[0];
  const float* mw1  = (const float*)d_in[1];
  const float* mb1  = (const float*)d_in[2];
  const float* mbn1 = (const float*)d_in[3];
  const float* mw2  = (const float*)d_in[4];
  const float* mb2  = (const float*)d_in[5];
  const float* mbn2 = (const float*)d_in[6];
  const float* pw1  = (const float*)d_in[7];
  const float* pb1  = (const float*)d_in[8];
  const float* pbn1 = (const float*)d_in[9];
  const float* pw2  = (const float*)d_in[10];
  const float* pb2  = (const float*)d_in[11];
  const float* pbn2 = (const float*)d_in[12];
  const float* rw1  = (const float*)d_in[13];
  const float* rb1  = (const float*)d_in[14];
  const float* rbn1 = (const float*)d_in[15];
  const float* rw2  = (const float*)d_in[16];
  const float* rb2  = (const float*)d_in[17];
  const float* rbn2 = (const float*)d_in[18];
  const float* lw1  = (const float*)d_in[19];
  const float* lb1  = (const float*)d_in[20];
  const float* lng  = (const float*)d_in[21];
  const float* lnb  = (const float*)d_in[22];
  const float* lw2  = (const float*)d_in[23];
  const float* lb2  = (const float*)d_in[24];

  float* ws = (float*)d_ws;
  float* out = (float*)d_out;

  float* fc    = ws + OFF_FC;
  float* mlog  = ws + OFF_MLOG;
  float* phb   = ws + OFF_PH;
  float* msp   = ws + OFF_MSP;
  float* psp   = ws + OFF_FC;  // reuse row-FFT buffer for upsampled phase
  float* rsum  = ws + OFF_RSUM;
  float* rcnt  = ws + OFF_RCNT;
  float* as1   = ws + OFF_AS1;
  float* as2   = ws + OFF_AS2;
  float* acnt  = ws + OFF_ACNT;
  float* mpool = ws + OFF_MPOOL;
  float* ppool = ws + OFF_PPOOL;
  float* rfb   = ws + OFF_RF;
  float* par   = ws + OFF_PAR;
  float* w2tm  = ws + OFF_W2TM;
  float* w2tp  = ws + OFF_W2TP;

  // zero the accumulator region (rsum..ppool = 3880 floats)
  hipMemsetAsync(rsum, 0, 3880 * sizeof(float), stream);

  prep_kernel<<<181, 256, 0, stream>>>(mw2, pw2, mb1, mbn1, mb2, mbn2, pb1, pbn1,
                                       pb2, pbn2, rb1, rbn1, rb2, rbn2, par, w2tm, w2tp);
  row_fft<<<12288, 256, 0, stream>>>(x, fc);
  col_fft_stats<<<dim3(129, 3, 16), 256, 0, stream>>>(fc, mlog, phb, rsum, rcnt,
                                                      as1, as2, acnt);
  upsample2<<<12288, 256, 0, stream>>>(mlog, phb, msp, psp);
  conv_branch<64, 8><<<dim3(16, 16, 16), 256, 0, stream>>>(
      msp, mw1, w2tm, par + 0, par + 64, par + 128, par + 192, mpool);
  conv_branch<32, 8><<<dim3(16, 16, 16), 256, 0, stream>>>(
      psp, pw1, w2tp, par + 256, par + 288, par + 320, par + 352, ppool);
  radial_conv<<<16, 128, 0, stream>>>(rsum, rcnt, rw1, rw2, par + 384, par + 416,
                                      par + 448, par + 480, rfb);
  final_mlp<<<16, 256, 0, stream>>>(mpool, ppool, rfb, as1, as2, acnt, lw1, lb1,
                                    lng, lnb, lw2, lb2, out);
}

// Round 2
// 1003.114 us; speedup vs baseline: 1.9088x; 1.9088x over previous
//
#include <hip/hip_runtime.h>
#include <math.h>

#define PI_F 3.14159274101257324f   // float(np.pi)

typedef __attribute__((ext_vector_type(8))) short bf16x8;   // 4 VGPRs
typedef __attribute__((ext_vector_type(4))) float f32x4;

// ---------------- workspace layout (float offsets) ----------------
static const size_t OFF_FC    = 0;                    // row-FFT complex out [B*C*256][129]*2 ; later reused as ph_sp
static const size_t OFF_MLOG  = 3170304;              // [B,C,256,129]
static const size_t OFF_PH    = 4755456;              // [B,C,256,129]
static const size_t OFF_MSP   = 6340608;              // [B,C,256,256]
static const size_t OFF_RSUM  = 9486336;              // [B,C,32]
static const size_t OFF_RCNT  = OFF_RSUM + 1536;      // [32]
static const size_t OFF_AS1   = OFF_RCNT + 32;        // [B,C,8]
static const size_t OFF_AS2   = OFF_AS1 + 384;        // [B,C,8]
static const size_t OFF_ACNT  = OFF_AS2 + 384;        // [8]
static const size_t OFF_MPOOL = OFF_ACNT + 8;         // [B,64]
static const size_t OFF_PPOOL = OFF_MPOOL + 1024;     // [B,32]
static const size_t OFF_RF    = OFF_PPOOL + 512;      // [B,32]
static const size_t OFF_PAR   = OFF_RF + 512;         // 512 folded BN params
static const size_t OFF_WBM   = OFF_PAR + 512;        // 36864 bf16 (18432 floats): mag w2 [9][64][64]
static const size_t OFF_WBP   = OFF_WBM + 18432;      // 9216 bf16 (4608 floats): ph w2 [9][32][32]
// param sub-offsets: sm1 0, tm1 64, sm2 128, tm2 192, sp1 256, tp1 288, sp2 320, tp2 352,
//                    sr1 384, tr1 416, sr2 448, tr2 480

__device__ __forceinline__ float fix_nan(float v, float pinf, float ninf) {
  if (isnan(v)) return 0.f;
  if (isinf(v)) return v > 0.f ? pinf : ninf;
  return v;
}

__device__ __forceinline__ unsigned short f2bf(float f) {
  unsigned u = __float_as_uint(f);
  unsigned r = (u + 0x7FFFu + ((u >> 16) & 1u)) >> 16;   // RNE (finite values only)
  return (unsigned short)r;
}

// ---------------- prep: fold BN, build bf16 [pos][oc][ci] conv2 weights ----------------
__device__ __forceinline__ void fold_bn(const float* bn, int C, int c, float cb,
                                        float* s, float* t) {
  float g = bn[c], b = bn[C + c], m = bn[2 * C + c], v = bn[3 * C + c];
  float sc = g / sqrtf(v + 1e-5f);
  *s = sc;
  *t = b + (cb - m) * sc;
}

__global__ __launch_bounds__(256) void prep_kernel(
    const float* __restrict__ mw2, const float* __restrict__ pw2,
    const float* __restrict__ mb1, const float* __restrict__ mbn1,
    const float* __restrict__ mb2, const float* __restrict__ mbn2,
    const float* __restrict__ pb1, const float* __restrict__ pbn1,
    const float* __restrict__ pb2, const float* __restrict__ pbn2,
    const float* __restrict__ rb1, const float* __restrict__ rbn1,
    const float* __restrict__ rb2, const float* __restrict__ rbn2,
    float* __restrict__ par, unsigned short* __restrict__ wbm,
    unsigned short* __restrict__ wbp) {
  int idx = blockIdx.x * 256 + threadIdx.x;
  if (idx < 36864) {
    int pos = idx / 4096, rem = idx % 4096;
    int oc = rem >> 6, ci = rem & 63;
    wbm[idx] = f2bf(mw2[(oc * 64 + ci) * 9 + pos]);
  } else if (idx < 46080) {
    int i = idx - 36864;
    int pos = i / 1024, rem = i % 1024;
    int oc = rem >> 5, ci = rem & 31;
    wbp[i] = f2bf(pw2[(oc * 32 + ci) * 9 + pos]);
  } else if (idx < 46336) {
    int i = idx - 46080;  // 0..255
    float s, t;
    if (i < 64)       { fold_bn(mbn1, 64, i, mb1[i], &s, &t);          par[i] = s;       par[64 + i] = t; }
    else if (i < 128) { int c = i - 64;  fold_bn(mbn2, 64, c, mb2[c], &s, &t); par[128 + c] = s; par[192 + c] = t; }
    else if (i < 160) { int c = i - 128; fold_bn(pbn1, 32, c, pb1[c], &s, &t); par[256 + c] = s; par[288 + c] = t; }
    else if (i < 192) { int c = i - 160; fold_bn(pbn2, 32, c, pb2[c], &s, &t); par[320 + c] = s; par[352 + c] = t; }
    else if (i < 224) { int c = i - 192; fold_bn(rbn1, 32, c, rb1[c], &s, &t); par[384 + c] = s; par[416 + c] = t; }
    else              { int c = i - 224; fold_bn(rbn2, 32, c, rb2[c], &s, &t); par[448 + c] = s; par[480 + c] = t; }
  }
}

// ---------------- row rFFT (along W): x[.,256] -> complex [.,129] ----------------
__global__ __launch_bounds__(256) void row_fft(const float* __restrict__ x,
                                               float* __restrict__ Fc) {
  const int blk = blockIdx.x;  // (b*3+c)*256 + y   (12288 blocks)
  const int tid = threadIdx.x;
  __shared__ float xr[256];
  __shared__ float2 tw[256];
  float v = x[(size_t)blk * 256 + tid];
  xr[tid] = fminf(fmaxf(v, -10.f), 10.f);
  float sn, cs;
  sincosf((float)(6.283185307179586 / 256.0) * (float)tid, &sn, &cs);
  tw[tid] = make_float2(cs, sn);
  __syncthreads();
  if (tid < 129) {
    float ar = 0.f, ai = 0.f;
    int t = 0;
#pragma unroll 4
    for (int w = 0; w < 256; ++w) {
      float xv = xr[w];
      float2 tt = tw[t];
      ar = fmaf(xv, tt.x, ar);
      ai = fmaf(xv, tt.y, ai);
      t = (t + tid) & 255;
    }
    float2* o = (float2*)Fc;
    o[(size_t)blk * 129 + tid] = make_float2(ar, -ai);
  }
}

// ---------------- column DFT (along H) + mag/phase + radial/azimuth stats ----------------
__global__ __launch_bounds__(256) void col_fft_stats(
    const float* __restrict__ Fc, float* __restrict__ mlog, float* __restrict__ ph,
    float* __restrict__ rsum, float* __restrict__ rcnt, float* __restrict__ as1,
    float* __restrict__ as2, float* __restrict__ acnt) {
  const int k = blockIdx.x, c = blockIdx.y, b = blockIdx.z;
  const int bc = b * 3 + c;
  const int tid = threadIdx.x;  // = output row j
  __shared__ float2 col[256];
  __shared__ float2 tw[256];
  __shared__ float l_rs[32], l_rc[32];
  __shared__ float l_s1[8], l_s2[8], l_ac[8];
  if (tid < 32) { l_rs[tid] = 0.f; l_rc[tid] = 0.f; }
  if (tid < 8)  { l_s1[tid] = 0.f; l_s2[tid] = 0.f; l_ac[tid] = 0.f; }
  const float2* fc = (const float2*)Fc;
  col[tid] = fc[((size_t)bc * 256 + tid) * 129 + k];
  float sn, cs;
  sincosf((float)(6.283185307179586 / 256.0) * (float)tid, &sn, &cs);
  tw[tid] = make_float2(cs, sn);
  __syncthreads();
  float gr = 0.f, gi = 0.f;
  int t = 0;
#pragma unroll 4
  for (int h = 0; h < 256; ++h) {
    float2 v = col[h];
    float2 w = tw[t];
    gr = fmaf(v.x, w.x, gr);
    gr = fmaf(v.y, w.y, gr);
    gi = fmaf(v.y, w.x, gi);
    gi = fmaf(v.x, -w.y, gi);
    t = (t + tid) & 255;
  }
  float mag = sqrtf(gr * gr + gi * gi);
  mag = fminf(fmaxf(mag, 1e-8f), 1e6f);
  float ml = fminf(fmaxf(log1pf(mag), -20.f), 20.f);
  float p = fminf(fmaxf(atan2f(gi, gr) / PI_F, -1.f), 1.f);
  mlog[((size_t)bc * 256 + tid) * 129 + k] = ml;
  ph[((size_t)bc * 256 + tid) * 129 + k] = p;
  // bins (bit-exact fp32 replication of the reference index math)
  float fy = (float)(tid < 128 ? tid : tid - 256) * (1.0f / 256.0f);
  float fx = (float)k * (1.0f / 256.0f);
  float rad = sqrtf(fx * fx + fy * fy);
  float denom = sqrtf(0.5f) + 1e-8f;
  int rb = (int)((rad / denom) * 31.0f);
  rb = rb < 0 ? 0 : (rb > 31 ? 31 : rb);
  float ang = atan2f(fy, fx + 1e-8f);
  int ab = (int)((ang + PI_F) / (2.0f * PI_F) * 8.0f);
  ab = ab < 0 ? 0 : (ab > 7 ? 7 : ab);
  atomicAdd(&l_rs[rb], mag);
  atomicAdd(&l_s1[ab], mag);
  atomicAdd(&l_s2[ab], mag * mag);
  if (bc == 0) {
    atomicAdd(&l_rc[rb], 1.0f);
    atomicAdd(&l_ac[ab], 1.0f);
  }
  __syncthreads();
  if (tid < 32) {
    atomicAdd(&rsum[bc * 32 + tid], l_rs[tid]);
    if (bc == 0) atomicAdd(&rcnt[tid], l_rc[tid]);
  } else if (tid < 40) {
    int a = tid - 32;
    atomicAdd(&as1[bc * 8 + a], l_s1[a]);
    atomicAdd(&as2[bc * 8 + a], l_s2[a]);
    if (bc == 0) atomicAdd(&acnt[a], l_ac[a]);
  }
}

// ---------------- bilinear W-upsample 129 -> 256 (H identity), both arrays ----------------
__global__ __launch_bounds__(256) void upsample2(const float* __restrict__ mlog,
                                                 const float* __restrict__ ph,
                                                 float* __restrict__ msp,
                                                 float* __restrict__ psp) {
  int idx = blockIdx.x * 256 + threadIdx.x;  // < 3145728
  if (idx >= 3145728) return;
  int xx = idx & 255;
  int row = idx >> 8;  // (b*3+c)*256 + y
  float src = ((float)xx + 0.5f) * (129.0f / 256.0f) - 0.5f;
  float fl = floorf(src);
  float w = src - fl;
  int x0 = (int)fl;
  int x1 = x0 + 1;
  x1 = x1 > 128 ? 128 : x1;
  x0 = x0 < 0 ? 0 : x0;
  const float* rm = mlog + (size_t)row * 129;
  const float* rp = ph + (size_t)row * 129;
  msp[idx] = rm[x0] * (1.f - w) + rm[x1] * w;
  psp[idx] = rp[x0] * (1.f - w) + rp[x1] * w;
}

// ---------------- fused conv1(VALU) -> conv2(MFMA implicit GEMM) -> pool ----------------
// 16x16 spatial tile per block; 4 waves; wave w owns pixel-rows [4w..4w+3] x ALL oc tiles.
// f1 stored bf16 [324 pixels][C2] with row stride C2+8 (16B aligned, uniform bank spread).
template <int C2>
__global__ __launch_bounds__(256) void conv_mfma(
    const float* __restrict__ inp, const float* __restrict__ w1,
    const unsigned short* __restrict__ wB,   // [9][C2][C2] bf16, [pos][oc][ci]
    const float* __restrict__ s1, const float* __restrict__ t1,
    const float* __restrict__ s2, const float* __restrict__ t2,
    float* __restrict__ pool) {
  constexpr int ST = C2 + 8;        // f1 row stride in bf16 elems (16B-aligned)
  constexpr int NT = C2 / 16;       // N tiles (oc)
  constexpr int KS = C2 / 32;       // K steps per kernel position

  __shared__ float s_in[3][20][20];
  __shared__ float s_w1[C2 * 27];
  __shared__ float s_sc1[C2], s_sh1[C2];
  __shared__ __align__(16) unsigned short s_f1[324 * ST];
  __shared__ float s_pool[C2];

  const int tid = threadIdx.x;
  const int b = blockIdx.z;
  const int tx0 = blockIdx.x * 16, ty0 = blockIdx.y * 16;
  const int lane = tid & 63, wv = tid >> 6;
  const int ln = lane & 15, q = lane >> 4;

  // stage input tile (halo 2 for conv1-of-halo-1)
  for (int idx = tid; idx < 1200; idx += 256) {
    int c = idx / 400, r = idx % 400, iy = r / 20, ix = r % 20;
    int gy = ty0 - 2 + iy, gx = tx0 - 2 + ix;
    float v = 0.f;
    if ((unsigned)gy < 256u && (unsigned)gx < 256u)
      v = inp[(((size_t)b * 3 + c) * 256 + gy) * 256 + gx];
    s_in[c][iy][ix] = v;
  }
  for (int idx = tid; idx < C2 * 27; idx += 256) s_w1[idx] = w1[idx];
  if (tid < C2) { s_sc1[tid] = s1[tid]; s_sh1[tid] = t1[tid]; s_pool[tid] = 0.f; }
  __syncthreads();

  // conv1 + BN + ReLU over 18x18 halo -> bf16 f1. Out-of-image pixels are TRUE ZERO
  // (conv2's SAME padding pads post-activation features, not conv1-of-padded-input).
  for (int p = tid; p < 324; p += 256) {
    int py = p / 18, px = p % 18;
    int gy = ty0 - 1 + py, gx = tx0 - 1 + px;
    bool inimg = ((unsigned)gy < 256u) && ((unsigned)gx < 256u);
    float xin[27];
#pragma unroll
    for (int c = 0; c < 3; ++c)
#pragma unroll
      for (int dy = 0; dy < 3; ++dy)
#pragma unroll
        for (int dx = 0; dx < 3; ++dx)
          xin[c * 9 + dy * 3 + dx] = s_in[c][py + dy][px + dx];
    for (int c2 = 0; c2 < C2; c2 += 2) {
      float a0 = 0.f, a1 = 0.f;
#pragma unroll
      for (int i = 0; i < 27; ++i) {
        a0 = fmaf(xin[i], s_w1[c2 * 27 + i], a0);
        a1 = fmaf(xin[i], s_w1[(c2 + 1) * 27 + i], a1);
      }
      float v0 = inimg ? fmaxf(fmaf(a0, s_sc1[c2], s_sh1[c2]), 0.f) : 0.f;
      float v1 = inimg ? fmaxf(fmaf(a1, s_sc1[c2 + 1], s_sh1[c2 + 1]), 0.f) : 0.f;
      unsigned pk = (unsigned)f2bf(v0) | ((unsigned)f2bf(v1) << 16);
      *(unsigned*)&s_f1[p * ST + c2] = pk;
    }
  }
  __syncthreads();

  // conv2 as 9-position implicit GEMM. A[m=lane&15][k=quad*8+j] from f1,
  // B[k][n=lane&15] from wB[pos][oc][ci] (8 contiguous ci per lane).
  f32x4 acc[4][NT];
#pragma unroll
  for (int mi = 0; mi < 4; ++mi)
#pragma unroll
    for (int nt = 0; nt < NT; ++nt)
      acc[mi][nt] = (f32x4){0.f, 0.f, 0.f, 0.f};

  const int mt0 = wv * 4;
  for (int pos = 0; pos < 9; ++pos) {
    const int ky = pos / 3, kx = pos % 3;
#pragma unroll
    for (int ks = 0; ks < KS; ++ks) {
      bf16x8 bfr[NT];
#pragma unroll
      for (int nt = 0; nt < NT; ++nt)
        bfr[nt] = *(const bf16x8*)&wB[((size_t)pos * C2 + nt * 16 + ln) * C2 + ks * 32 + q * 8];
#pragma unroll
      for (int mi = 0; mi < 4; ++mi) {
        const int row = mt0 + mi + ky;                 // 0..17
        bf16x8 af = *(const bf16x8*)&s_f1[(row * 18 + ln + kx) * ST + ks * 32 + q * 8];
#pragma unroll
        for (int nt = 0; nt < NT; ++nt)
          acc[mi][nt] = __builtin_amdgcn_mfma_f32_16x16x32_bf16(af, bfr[nt], acc[mi][nt], 0, 0, 0);
      }
    }
  }

  // epilogue: BN+ReLU, pool partials. D layout: col(oc)=lane&15, rows covered by quad*4+reg.
#pragma unroll
  for (int nt = 0; nt < NT; ++nt) {
    const int oc = nt * 16 + ln;
    const float sc = s2[oc], sh = t2[oc];
    float v = 0.f;
#pragma unroll
    for (int mi = 0; mi < 4; ++mi)
#pragma unroll
      for (int r = 0; r < 4; ++r)
        v += fmaxf(fmaf(acc[mi][nt][r], sc, sh), 0.f);
    v += __shfl_xor(v, 16);
    v += __shfl_xor(v, 32);
    if (q == 0) atomicAdd(&s_pool[oc], v);
  }
  __syncthreads();
  if (tid < C2) atomicAdd(&pool[b * C2 + tid], s_pool[tid]);
}

// ---------------- radial 1d conv branch ----------------
__global__ __launch_bounds__(128) void radial_conv(
    const float* __restrict__ rsum, const float* __restrict__ rcnt,
    const float* __restrict__ rw1, const float* __restrict__ rw2,
    const float* __restrict__ sr1, const float* __restrict__ tr1,
    const float* __restrict__ sr2, const float* __restrict__ tr2,
    float* __restrict__ rf) {
  int b = blockIdx.x, t = threadIdx.x;
  __shared__ float rad[3][32];
  __shared__ float f1[32][32];
  __shared__ float f2[32][32];
  if (t < 96) {
    int c = t / 32, i = t % 32;
    float cnt = fmaxf(rcnt[i], 1.0f);
    float v = rsum[(b * 3 + c) * 32 + i] / cnt;
    rad[c][i] = fminf(fmaxf(v, 0.f), 1e6f);
  }
  __syncthreads();
  for (int idx = t; idx < 1024; idx += 128) {
    int oc = idx >> 5, i = idx & 31;
    float a = 0.f;
    for (int c = 0; c < 3; ++c)
#pragma unroll
      for (int d = 0; d < 3; ++d) {
        int ii = i + d - 1;
        if (ii >= 0 && ii < 32) a = fmaf(rad[c][ii], rw1[(oc * 3 + c) * 3 + d], a);
      }
    f1[oc][i] = fmaxf(fmaf(a, sr1[oc], tr1[oc]), 0.f);
  }
  __syncthreads();
  for (int idx = t; idx < 1024; idx += 128) {
    int oc = idx >> 5, i = idx & 31;
    float a = 0.f;
    for (int c = 0; c < 32; ++c)
#pragma unroll
      for (int d = 0; d < 3; ++d) {
        int ii = i + d - 1;
        if (ii >= 0 && ii < 32) a = fmaf(f1[c][ii], rw2[(oc * 32 + c) * 3 + d], a);
      }
    f2[oc][i] = fmaxf(fmaf(a, sr2[oc], tr2[oc]), 0.f);
  }
  __syncthreads();
  if (t < 32) {
    float s = 0.f;
    for (int i = 0; i < 32; ++i) s += f2[t][i];
    rf[b * 32 + t] = s * (1.0f / 32.0f);
  }
}

// ---------------- final: comb assembly, linear, layernorm, relu, linear ----------------
__global__ __launch_bounds__(256) void final_mlp(
    const float* __restrict__ mpool, const float* __restrict__ ppool,
    const float* __restrict__ rf, const float* __restrict__ as1,
    const float* __restrict__ as2, const float* __restrict__ acnt,
    const float* __restrict__ lw1, const float* __restrict__ lb1,
    const float* __restrict__ lng, const float* __restrict__ lnb,
    const float* __restrict__ lw2, const float* __restrict__ lb2,
    float* __restrict__ out) {
  int b = blockIdx.x, t = threadIdx.x;
  __shared__ float comb[176];
  __shared__ float red[256];
  __shared__ float hrelu[256];
  __shared__ float s_mu, s_var;
  if (t < 64) comb[t] = fix_nan(mpool[b * 64 + t] * (1.0f / 65536.0f), 1e4f, -1e4f);
  else if (t < 96) comb[t] = fix_nan(ppool[b * 32 + t - 64] * (1.0f / 65536.0f), 1e4f, -1e4f);
  else if (t < 128) comb[t] = fix_nan(rf[b * 32 + t - 96], 1e4f, -1e4f);
  else if (t < 176) {
    int j = t - 128;
    int a = j / 6, r = j % 6, m = r / 3, c = r % 3;
    float cnt = acnt[a];
    float v = 0.f;  // empty sector -> NaN -> nan_to_num -> 0
    if (cnt > 0.f) {
      float s1v = as1[(b * 3 + c) * 8 + a], s2v = as2[(b * 3 + c) * 8 + a];
      float mean = s1v / cnt;
      if (m == 0)
        v = mean;
      else {
        float var = (s2v - cnt * mean * mean) / fmaxf(cnt - 1.f, 1.f);
        v = sqrtf(fmaxf(var, 0.f));
      }
    }
    comb[t] = fix_nan(v, 1e4f, -1e4f);
  }
  __syncthreads();
  float h = lb1[t];
  const float* wr = lw1 + t * 176;
#pragma unroll 8
  for (int j = 0; j < 176; ++j) h = fmaf(comb[j], wr[j], h);
  red[t] = h;
  __syncthreads();
  for (int s = 128; s > 0; s >>= 1) {
    if (t < s) red[t] += red[t + s];
    __syncthreads();
  }
  if (t == 0) s_mu = red[0] * (1.0f / 256.0f);
  __syncthreads();
  float mu = s_mu;
  float d = h - mu;
  red[t] = d * d;
  __syncthreads();
  for (int s = 128; s > 0; s >>= 1) {
    if (t < s) red[t] += red[t + s];
    __syncthreads();
  }
  if (t == 0) s_var = red[0] * (1.0f / 256.0f);
  __syncthreads();
  float hn = d / sqrtf(s_var + 1e-5f) * lng[t] + lnb[t];
  hrelu[t] = fmaxf(hn, 0.f);
  __syncthreads();
  if (t < 128) {
    float o = lb2[t];
    const float* w2r = lw2 + t * 256;
#pragma unroll 8
    for (int j = 0; j < 256; ++j) o = fmaf(hrelu[j], w2r[j], o);
    o = fminf(fmaxf(o, -100.f), 100.f);
    out[b * 128 + t] = fix_nan(o, 100.f, -100.f);
  }
}

// ---------------- host launcher ----------------
extern "C" void kernel_launch(void* const* d_in, const int* in_sizes, int n_in,
                              void* d_out, int out_size, void* d_ws, size_t ws_size,
                              hipStream_t stream) {
  const float* x    = (const float*)d_in[0];
  const float* mw1  = (const float*)d_in[1];
  const float* mb1  = (const float*)d_in[2];
  const float* mbn1 = (const float*)d_in[3];
  const float* mw2  = (const float*)d_in[4];
  const float* mb2  = (const float*)d_in[5];
  const float* mbn2 = (const float*)d_in[6];
  const float* pw1  = (const float*)d_in[7];
  const float* pb1  = (const float*)d_in[8];
  const float* pbn1 = (const float*)d_in[9];
  const float* pw2  = (const float*)d_in[10];
  const float* pb2  = (const float*)d_in[11];
  const float* pbn2 = (const float*)d_in[12];
  const float* rw1  = (const float*)d_in[13];
  const float* rb1  = (const float*)d_in[14];
  const float* rbn1 = (const float*)d_in[15];
  const float* rw2  = (const float*)d_in[16];
  const float* rb2  = (const float*)d_in[17];
  const float* rbn2 = (const float*)d_in[18];
  const float* lw1  = (const float*)d_in[19];
  const float* lb1  = (const float*)d_in[20];
  const float* lng  = (const float*)d_in[21];
  const float* lnb  = (const float*)d_in[22];
  const float* lw2  = (const float*)d_in[23];
  const float* lb2  = (const float*)d_in[24];

  float* ws = (float*)d_ws;
  float* out = (float*)d_out;

  float* fc    = ws + OFF_FC;
  float* mlog  = ws + OFF_MLOG;
  float* phb   = ws + OFF_PH;
  float* msp   = ws + OFF_MSP;
  float* psp   = ws + OFF_FC;  // reuse row-FFT buffer for upsampled phase
  float* rsum  = ws + OFF_RSUM;
  float* rcnt  = ws + OFF_RCNT;
  float* as1   = ws + OFF_AS1;
  float* as2   = ws + OFF_AS2;
  float* acnt  = ws + OFF_ACNT;
  float* mpool = ws + OFF_MPOOL;
  float* ppool = ws + OFF_PPOOL;
  float* rfb   = ws + OFF_RF;
  float* par   = ws + OFF_PAR;
  unsigned short* wbm = (unsigned short*)(ws + OFF_WBM);
  unsigned short* wbp = (unsigned short*)(ws + OFF_WBP);

  // zero the accumulator region (rsum..ppool = 3880 floats)
  hipMemsetAsync(rsum, 0, 3880 * sizeof(float), stream);

  prep_kernel<<<181, 256, 0, stream>>>(mw2, pw2, mb1, mbn1, mb2, mbn2, pb1, pbn1,
                                       pb2, pbn2, rb1, rbn1, rb2, rbn2, par, wbm, wbp);
  row_fft<<<12288, 256, 0, stream>>>(x, fc);
  col_fft_stats<<<dim3(129, 3, 16), 256, 0, stream>>>(fc, mlog, phb, rsum, rcnt,
                                                      as1, as2, acnt);
  upsample2<<<12288, 256, 0, stream>>>(mlog, phb, msp, psp);
  conv_mfma<64><<<dim3(16, 16, 16), 256, 0, stream>>>(
      msp, mw1, wbm, par + 0, par + 64, par + 128, par + 192, mpool);
  conv_mfma<32><<<dim3(16, 16, 16), 256, 0, stream>>>(
      psp, pw1, wbp, par + 256, par + 288, par + 320, par + 352, ppool);
  radial_conv<<<16, 128, 0, stream>>>(rsum, rcnt, rw1, rw2, par + 384, par + 416,
                                      par + 448, par + 480, rfb);
  final_mlp<<<16, 256, 0, stream>>>(mpool, ppool, rfb, as1, as2, acnt, lw1, lb1,
                                    lng, lnb, lw2, lb2, out);
}

// Round 3
// 637.191 us; speedup vs baseline: 3.0049x; 1.5743x over previous
//
#include <hip/hip_runtime.h>
#include <math.h>

#define PI_F 3.14159274101257324f   // float(np.pi)

typedef __attribute__((ext_vector_type(8))) short bf16x8;   // 4 VGPRs
typedef __attribute__((ext_vector_type(4))) float f32x4;

// ---------------- workspace layout (float offsets) ----------------
static const size_t OFF_FC    = 0;                    // row-FFT complex out [B*C*256][129]*2
static const size_t OFF_MLOG  = 3170304;              // [B,C,256,129]
static const size_t OFF_PH    = 4755456;              // [B,C,256,129]
static const size_t OFF_RSUM  = 9486336;              // [B,C,32]
static const size_t OFF_RCNT  = OFF_RSUM + 1536;      // [32]
static const size_t OFF_AS1   = OFF_RCNT + 32;        // [B,C,8]
static const size_t OFF_AS2   = OFF_AS1 + 384;        // [B,C,8]
static const size_t OFF_ACNT  = OFF_AS2 + 384;        // [8]
static const size_t OFF_MPOOL = OFF_ACNT + 8;         // [B,64]
static const size_t OFF_PPOOL = OFF_MPOOL + 1024;     // [B,32]
static const size_t OFF_RF    = OFF_PPOOL + 512;      // [B,32]
static const size_t OFF_PAR   = OFF_RF + 512;         // 512 folded BN params
static const size_t OFF_WBM   = OFF_PAR + 512;        // 18432 floats: mag conv2 w [9][64][64] bf16
static const size_t OFF_WBP   = OFF_WBM + 18432;      // 4608 floats: ph conv2 w [9][32][32] bf16
static const size_t OFF_W1BM  = OFF_WBP + 4608;       // 1024 floats: mag conv1 w [64][32] bf16
static const size_t OFF_W1BP  = OFF_W1BM + 1024;      // 512 floats:  ph conv1 w [32][32] bf16
// param sub-offsets: sm1 0, tm1 64, sm2 128, tm2 192, sp1 256, tp1 288, sp2 320, tp2 352,
//                    sr1 384, tr1 416, sr2 448, tr2 480

__device__ __forceinline__ float fix_nan(float v, float pinf, float ninf) {
  if (isnan(v)) return 0.f;
  if (isinf(v)) return v > 0.f ? pinf : ninf;
  return v;
}

__device__ __forceinline__ unsigned short f2bf(float f) {
  unsigned u = __float_as_uint(f);
  unsigned r = (u + 0x7FFFu + ((u >> 16) & 1u)) >> 16;   // RNE (finite values only)
  return (unsigned short)r;
}

// ---------------- prep: fold BN, build bf16 weight layouts ----------------
__device__ __forceinline__ void fold_bn(const float* bn, int C, int c, float cb,
                                        float* s, float* t) {
  float g = bn[c], b = bn[C + c], m = bn[2 * C + c], v = bn[3 * C + c];
  float sc = g / sqrtf(v + 1e-5f);
  *s = sc;
  *t = b + (cb - m) * sc;
}

__global__ __launch_bounds__(256) void prep_kernel(
    const float* __restrict__ mw1, const float* __restrict__ pw1,
    const float* __restrict__ mw2, const float* __restrict__ pw2,
    const float* __restrict__ mb1, const float* __restrict__ mbn1,
    const float* __restrict__ mb2, const float* __restrict__ mbn2,
    const float* __restrict__ pb1, const float* __restrict__ pbn1,
    const float* __restrict__ pb2, const float* __restrict__ pbn2,
    const float* __restrict__ rb1, const float* __restrict__ rbn1,
    const float* __restrict__ rb2, const float* __restrict__ rbn2,
    float* __restrict__ par, unsigned short* __restrict__ wbm,
    unsigned short* __restrict__ wbp, unsigned short* __restrict__ w1bm,
    unsigned short* __restrict__ w1bp) {
  int idx = blockIdx.x * 256 + threadIdx.x;
  if (idx < 36864) {
    int pos = idx / 4096, rem = idx % 4096;
    int oc = rem >> 6, ci = rem & 63;
    wbm[idx] = f2bf(mw2[(oc * 64 + ci) * 9 + pos]);
  } else if (idx < 46080) {
    int i = idx - 36864;
    int pos = i / 1024, rem = i % 1024;
    int oc = rem >> 5, ci = rem & 31;
    wbp[i] = f2bf(pw2[(oc * 32 + ci) * 9 + pos]);
  } else if (idx < 46336) {
    int i = idx - 46080;  // 0..255
    float s, t;
    if (i < 64)       { fold_bn(mbn1, 64, i, mb1[i], &s, &t);          par[i] = s;       par[64 + i] = t; }
    else if (i < 128) { int c = i - 64;  fold_bn(mbn2, 64, c, mb2[c], &s, &t); par[128 + c] = s; par[192 + c] = t; }
    else if (i < 160) { int c = i - 128; fold_bn(pbn1, 32, c, pb1[c], &s, &t); par[256 + c] = s; par[288 + c] = t; }
    else if (i < 192) { int c = i - 160; fold_bn(pbn2, 32, c, pb2[c], &s, &t); par[320 + c] = s; par[352 + c] = t; }
    else if (i < 224) { int c = i - 192; fold_bn(rbn1, 32, c, rb1[c], &s, &t); par[384 + c] = s; par[416 + c] = t; }
    else              { int c = i - 224; fold_bn(rbn2, 32, c, rb2[c], &s, &t); par[448 + c] = s; par[480 + c] = t; }
  } else if (idx < 48384) {
    int i = idx - 46336;                 // conv1 mag weights [oc][k], k = c*9+dy*3+dx, pad 27..31 = 0
    int oc = i >> 5, k = i & 31;
    w1bm[i] = (k < 27) ? f2bf(mw1[oc * 27 + k]) : (unsigned short)0;
  } else if (idx < 49408) {
    int i = idx - 48384;
    int oc = i >> 5, k = i & 31;
    w1bp[i] = (k < 27) ? f2bf(pw1[oc * 27 + k]) : (unsigned short)0;
  }
}

// ---------------- row rFFT (along W): x[.,256] -> complex [.,129] ----------------
__global__ __launch_bounds__(256) void row_fft(const float* __restrict__ x,
                                               float* __restrict__ Fc) {
  const int blk = blockIdx.x;  // (b*3+c)*256 + y   (12288 blocks)
  const int tid = threadIdx.x;
  __shared__ float xr[256];
  __shared__ float2 tw[256];
  float v = x[(size_t)blk * 256 + tid];
  xr[tid] = fminf(fmaxf(v, -10.f), 10.f);
  float sn, cs;
  sincosf((float)(6.283185307179586 / 256.0) * (float)tid, &sn, &cs);
  tw[tid] = make_float2(cs, sn);
  __syncthreads();
  if (tid < 129) {
    float ar = 0.f, ai = 0.f;
    int t = 0;
#pragma unroll 4
    for (int w = 0; w < 256; ++w) {
      float xv = xr[w];
      float2 tt = tw[t];
      ar = fmaf(xv, tt.x, ar);
      ai = fmaf(xv, tt.y, ai);
      t = (t + tid) & 255;
    }
    float2* o = (float2*)Fc;
    o[(size_t)blk * 129 + tid] = make_float2(ar, -ai);
  }
}

// ---------------- column DFT (along H) + mag/phase + radial/azimuth stats ----------------
__global__ __launch_bounds__(256) void col_fft_stats(
    const float* __restrict__ Fc, float* __restrict__ mlog, float* __restrict__ ph,
    float* __restrict__ rsum, float* __restrict__ rcnt, float* __restrict__ as1,
    float* __restrict__ as2, float* __restrict__ acnt) {
  const int k = blockIdx.x, c = blockIdx.y, b = blockIdx.z;
  const int bc = b * 3 + c;
  const int tid = threadIdx.x;  // = output row j
  __shared__ float2 col[256];
  __shared__ float2 tw[256];
  __shared__ float l_rs[32], l_rc[32];
  __shared__ float l_s1[8], l_s2[8], l_ac[8];
  if (tid < 32) { l_rs[tid] = 0.f; l_rc[tid] = 0.f; }
  if (tid < 8)  { l_s1[tid] = 0.f; l_s2[tid] = 0.f; l_ac[tid] = 0.f; }
  const float2* fc = (const float2*)Fc;
  col[tid] = fc[((size_t)bc * 256 + tid) * 129 + k];
  float sn, cs;
  sincosf((float)(6.283185307179586 / 256.0) * (float)tid, &sn, &cs);
  tw[tid] = make_float2(cs, sn);
  __syncthreads();
  float gr = 0.f, gi = 0.f;
  int t = 0;
#pragma unroll 4
  for (int h = 0; h < 256; ++h) {
    float2 v = col[h];
    float2 w = tw[t];
    gr = fmaf(v.x, w.x, gr);
    gr = fmaf(v.y, w.y, gr);
    gi = fmaf(v.y, w.x, gi);
    gi = fmaf(v.x, -w.y, gi);
    t = (t + tid) & 255;
  }
  float mag = sqrtf(gr * gr + gi * gi);
  mag = fminf(fmaxf(mag, 1e-8f), 1e6f);
  float ml = fminf(fmaxf(log1pf(mag), -20.f), 20.f);
  float p = fminf(fmaxf(atan2f(gi, gr) / PI_F, -1.f), 1.f);
  mlog[((size_t)bc * 256 + tid) * 129 + k] = ml;
  ph[((size_t)bc * 256 + tid) * 129 + k] = p;
  // bins (bit-exact fp32 replication of the reference index math)
  float fy = (float)(tid < 128 ? tid : tid - 256) * (1.0f / 256.0f);
  float fx = (float)k * (1.0f / 256.0f);
  float rad = sqrtf(fx * fx + fy * fy);
  float denom = sqrtf(0.5f) + 1e-8f;
  int rb = (int)((rad / denom) * 31.0f);
  rb = rb < 0 ? 0 : (rb > 31 ? 31 : rb);
  float ang = atan2f(fy, fx + 1e-8f);
  int ab = (int)((ang + PI_F) / (2.0f * PI_F) * 8.0f);
  ab = ab < 0 ? 0 : (ab > 7 ? 7 : ab);
  atomicAdd(&l_rs[rb], mag);
  atomicAdd(&l_s1[ab], mag);
  atomicAdd(&l_s2[ab], mag * mag);
  if (bc == 0) {
    atomicAdd(&l_rc[rb], 1.0f);
    atomicAdd(&l_ac[ab], 1.0f);
  }
  __syncthreads();
  if (tid < 32) {
    atomicAdd(&rsum[bc * 32 + tid], l_rs[tid]);
    if (bc == 0) atomicAdd(&rcnt[tid], l_rc[tid]);
  } else if (tid < 40) {
    int a = tid - 32;
    atomicAdd(&as1[bc * 8 + a], l_s1[a]);
    atomicAdd(&as2[bc * 8 + a], l_s2[a]);
    if (bc == 0) atomicAdd(&acnt[a], l_ac[a]);
  }
}

// ---------------- fused upsample -> conv1(MFMA) -> conv2(MFMA) -> pool ----------------
// 16x16 spatial tile per block; 4 waves. conv1: one K=32 MFMA step over the 27-tap
// im2col patch (A built in-register from the fp32 s_in tile). conv2: implicit GEMM
// with hoisted A-fragments. Bilinear 129->256 W-upsample fused into staging.
template <int C2>
__global__ __launch_bounds__(256, (C2 == 64 ? 3 : 4)) void conv_mfma(
    const float* __restrict__ src,           // [B,3,256,129] spectral plane
    const unsigned short* __restrict__ w1b,  // [C2][32] bf16 conv1 weights
    const unsigned short* __restrict__ wB,   // [9][C2][C2] bf16 conv2 [pos][oc][ci]
    const float* __restrict__ s1, const float* __restrict__ t1,
    const float* __restrict__ s2, const float* __restrict__ t2,
    float* __restrict__ pool) {
  constexpr int ST = C2 + 8;        // f1 row stride in bf16 elems (16B-aligned)
  constexpr int NT = C2 / 16;       // N tiles (oc)
  constexpr int KS = C2 / 32;       // conv2 K steps per kernel position

  __shared__ float s_in[3][20][20];
  __shared__ float s_sc1[C2], s_sh1[C2];
  __shared__ __align__(16) unsigned short s_f1[324 * ST];
  __shared__ float s_pool[C2];

  const int tid = threadIdx.x;
  const int b = blockIdx.z;
  const int tx0 = blockIdx.x * 16, ty0 = blockIdx.y * 16;
  const int lane = tid & 63, wv = tid >> 6;
  const int ln = lane & 15, q = lane >> 4;

  // stage input tile (halo 2) with fused bilinear W-upsample (129 -> 256)
  for (int idx = tid; idx < 1200; idx += 256) {
    int c = idx / 400, r = idx % 400, iy = r / 20, ix = r % 20;
    int gy = ty0 - 2 + iy, gx = tx0 - 2 + ix;
    float v = 0.f;
    if ((unsigned)gy < 256u && (unsigned)gx < 256u) {
      float srcx = ((float)gx + 0.5f) * (129.0f / 256.0f) - 0.5f;
      float fl = floorf(srcx);
      float w = srcx - fl;
      int x0 = (int)fl, x1 = x0 + 1;
      x0 = x0 < 0 ? 0 : x0;
      x1 = x1 > 128 ? 128 : x1;
      const float* rowp = src + ((size_t)(b * 3 + c) * 256 + gy) * 129;
      v = rowp[x0] * (1.f - w) + rowp[x1] * w;
    }
    s_in[c][iy][ix] = v;
  }
  if (tid < C2) { s_sc1[tid] = s1[tid]; s_sh1[tid] = t1[tid]; s_pool[tid] = 0.f; }

  // conv1 B-fragments (kept in registers; B[k][n]: n=lane&15 -> oc, k=q*8+j contiguous)
  bf16x8 b1[NT];
#pragma unroll
  for (int nt = 0; nt < NT; ++nt)
    b1[nt] = *(const bf16x8*)&w1b[(nt * 16 + ln) * 32 + q * 8];

  __syncthreads();

  // ---- phase 1: conv1 via MFMA over 18x18 halo (padded to 336 px = 21 m-tiles) ----
  // Out-of-image pixels forced to TRUE ZERO in s_f1 (conv2 pads post-activation feat).
  for (int mt = wv; mt < 21; mt += 4) {
    int p = mt * 16 + ln;
    int pc = p < 324 ? p : 0;          // dummy pixel for pad rows (results discarded)
    int py = pc / 18, px = pc - py * 18;
    bf16x8 af;
#pragma unroll
    for (int j = 0; j < 8; ++j) {
      int k = q * 8 + j;               // k = c*9 + dy*3 + dx
      float v = 0.f;
      if (k < 27) {
        int c = k / 9, rr = k - c * 9, dy = rr / 3, dx = rr - dy * 3;
        v = s_in[c][py + dy][px + dx];
      }
      af[j] = (short)f2bf(v);
    }
    f32x4 c1[NT];
#pragma unroll
    for (int nt = 0; nt < NT; ++nt)
      c1[nt] = __builtin_amdgcn_mfma_f32_16x16x32_bf16(
          af, b1[nt], (f32x4){0.f, 0.f, 0.f, 0.f}, 0, 0, 0);
    // write back: pixel = mt*16 + q*4 + r, oc = nt*16 + ln (C layout: col=lane&15)
#pragma unroll
    for (int r = 0; r < 4; ++r) {
      int pe = mt * 16 + q * 4 + r;
      if (pe < 324) {
        int ey = pe / 18, ex = pe - ey * 18;
        int gy = ty0 - 1 + ey, gx = tx0 - 1 + ex;
        bool inim = ((unsigned)gy < 256u) && ((unsigned)gx < 256u);
#pragma unroll
        for (int nt = 0; nt < NT; ++nt) {
          int oc = nt * 16 + ln;
          float v = inim ? fmaxf(fmaf(c1[nt][r], s_sc1[oc], s_sh1[oc]), 0.f) : 0.f;
          s_f1[pe * ST + oc] = f2bf(v);
        }
      }
    }
  }
  __syncthreads();

  // ---- phase 2: conv2 implicit GEMM, A-fragments hoisted across ky ----
  f32x4 acc[4][NT];
#pragma unroll
  for (int mi = 0; mi < 4; ++mi)
#pragma unroll
    for (int nt = 0; nt < NT; ++nt)
      acc[mi][nt] = (f32x4){0.f, 0.f, 0.f, 0.f};

  const int mt0 = wv * 4;
  for (int kx = 0; kx < 3; ++kx) {
#pragma unroll
    for (int ks = 0; ks < KS; ++ks) {
      bf16x8 a[6];
#pragma unroll
      for (int rr = 0; rr < 6; ++rr)
        a[rr] = *(const bf16x8*)&s_f1[((mt0 + rr) * 18 + ln + kx) * ST + ks * 32 + q * 8];
#pragma unroll
      for (int ky = 0; ky < 3; ++ky) {
        bf16x8 bfr[NT];
#pragma unroll
        for (int nt = 0; nt < NT; ++nt)
          bfr[nt] = *(const bf16x8*)&wB[((size_t)(ky * 3 + kx) * C2 + nt * 16 + ln) * C2 + ks * 32 + q * 8];
#pragma unroll
        for (int mi = 0; mi < 4; ++mi)
#pragma unroll
          for (int nt = 0; nt < NT; ++nt)
            acc[mi][nt] = __builtin_amdgcn_mfma_f32_16x16x32_bf16(
                a[mi + ky], bfr[nt], acc[mi][nt], 0, 0, 0);
      }
    }
  }

  // epilogue: BN+ReLU, pool partials. D layout: col(oc)=lane&15, rows = quad*4+reg.
#pragma unroll
  for (int nt = 0; nt < NT; ++nt) {
    const int oc = nt * 16 + ln;
    const float sc = s2[oc], sh = t2[oc];
    float v = 0.f;
#pragma unroll
    for (int mi = 0; mi < 4; ++mi)
#pragma unroll
      for (int r = 0; r < 4; ++r)
        v += fmaxf(fmaf(acc[mi][nt][r], sc, sh), 0.f);
    v += __shfl_xor(v, 16);
    v += __shfl_xor(v, 32);
    if (q == 0) atomicAdd(&s_pool[oc], v);
  }
  __syncthreads();
  if (tid < C2) atomicAdd(&pool[b * C2 + tid], s_pool[tid]);
}

// ---------------- radial 1d conv branch ----------------
__global__ __launch_bounds__(128) void radial_conv(
    const float* __restrict__ rsum, const float* __restrict__ rcnt,
    const float* __restrict__ rw1, const float* __restrict__ rw2,
    const float* __restrict__ sr1, const float* __restrict__ tr1,
    const float* __restrict__ sr2, const float* __restrict__ tr2,
    float* __restrict__ rf) {
  int b = blockIdx.x, t = threadIdx.x;
  __shared__ float rad[3][32];
  __shared__ float f1[32][32];
  __shared__ float f2[32][32];
  if (t < 96) {
    int c = t / 32, i = t % 32;
    float cnt = fmaxf(rcnt[i], 1.0f);
    float v = rsum[(b * 3 + c) * 32 + i] / cnt;
    rad[c][i] = fminf(fmaxf(v, 0.f), 1e6f);
  }
  __syncthreads();
  for (int idx = t; idx < 1024; idx += 128) {
    int oc = idx >> 5, i = idx & 31;
    float a = 0.f;
    for (int c = 0; c < 3; ++c)
#pragma unroll
      for (int d = 0; d < 3; ++d) {
        int ii = i + d - 1;
        if (ii >= 0 && ii < 32) a = fmaf(rad[c][ii], rw1[(oc * 3 + c) * 3 + d], a);
      }
    f1[oc][i] = fmaxf(fmaf(a, sr1[oc], tr1[oc]), 0.f);
  }
  __syncthreads();
  for (int idx = t; idx < 1024; idx += 128) {
    int oc = idx >> 5, i = idx & 31;
    float a = 0.f;
    for (int c = 0; c < 32; ++c)
#pragma unroll
      for (int d = 0; d < 3; ++d) {
        int ii = i + d - 1;
        if (ii >= 0 && ii < 32) a = fmaf(f1[c][ii], rw2[(oc * 32 + c) * 3 + d], a);
      }
    f2[oc][i] = fmaxf(fmaf(a, sr2[oc], tr2[oc]), 0.f);
  }
  __syncthreads();
  if (t < 32) {
    float s = 0.f;
    for (int i = 0; i < 32; ++i) s += f2[t][i];
    rf[b * 32 + t] = s * (1.0f / 32.0f);
  }
}

// ---------------- final: comb assembly, linear, layernorm, relu, linear ----------------
__global__ __launch_bounds__(256) void final_mlp(
    const float* __restrict__ mpool, const float* __restrict__ ppool,
    const float* __restrict__ rf, const float* __restrict__ as1,
    const float* __restrict__ as2, const float* __restrict__ acnt,
    const float* __restrict__ lw1, const float* __restrict__ lb1,
    const float* __restrict__ lng, const float* __restrict__ lnb,
    const float* __restrict__ lw2, const float* __restrict__ lb2,
    float* __restrict__ out) {
  int b = blockIdx.x, t = threadIdx.x;
  __shared__ float comb[176];
  __shared__ float red[256];
  __shared__ float hrelu[256];
  __shared__ float s_mu, s_var;
  if (t < 64) comb[t] = fix_nan(mpool[b * 64 + t] * (1.0f / 65536.0f), 1e4f, -1e4f);
  else if (t < 96) comb[t] = fix_nan(ppool[b * 32 + t - 64] * (1.0f / 65536.0f), 1e4f, -1e4f);
  else if (t < 128) comb[t] = fix_nan(rf[b * 32 + t - 96], 1e4f, -1e4f);
  else if (t < 176) {
    int j = t - 128;
    int a = j / 6, r = j % 6, m = r / 3, c = r % 3;
    float cnt = acnt[a];
    float v = 0.f;  // empty sector -> NaN -> nan_to_num -> 0
    if (cnt > 0.f) {
      float s1v = as1[(b * 3 + c) * 8 + a], s2v = as2[(b * 3 + c) * 8 + a];
      float mean = s1v / cnt;
      if (m == 0)
        v = mean;
      else {
        float var = (s2v - cnt * mean * mean) / fmaxf(cnt - 1.f, 1.f);
        v = sqrtf(fmaxf(var, 0.f));
      }
    }
    comb[t] = fix_nan(v, 1e4f, -1e4f);
  }
  __syncthreads();
  float h = lb1[t];
  const float* wr = lw1 + t * 176;
#pragma unroll 8
  for (int j = 0; j < 176; ++j) h = fmaf(comb[j], wr[j], h);
  red[t] = h;
  __syncthreads();
  for (int s = 128; s > 0; s >>= 1) {
    if (t < s) red[t] += red[t + s];
    __syncthreads();
  }
  if (t == 0) s_mu = red[0] * (1.0f / 256.0f);
  __syncthreads();
  float mu = s_mu;
  float d = h - mu;
  red[t] = d * d;
  __syncthreads();
  for (int s = 128; s > 0; s >>= 1) {
    if (t < s) red[t] += red[t + s];
    __syncthreads();
  }
  if (t == 0) s_var = red[0] * (1.0f / 256.0f);
  __syncthreads();
  float hn = d / sqrtf(s_var + 1e-5f) * lng[t] + lnb[t];
  hrelu[t] = fmaxf(hn, 0.f);
  __syncthreads();
  if (t < 128) {
    float o = lb2[t];
    const float* w2r = lw2 + t * 256;
#pragma unroll 8
    for (int j = 0; j < 256; ++j) o = fmaf(hrelu[j], w2r[j], o);
    o = fminf(fmaxf(o, -100.f), 100.f);
    out[b * 128 + t] = fix_nan(o, 100.f, -100.f);
  }
}

// ---------------- host launcher ----------------
extern "C" void kernel_launch(void* const* d_in, const int* in_sizes, int n_in,
                              void* d_out, int out_size, void* d_ws, size_t ws_size,
                              hipStream_t stream) {
  const float* x    = (const float*)d_in[0];
  const float* mw1  = (const float*)d_in[1];
  const float* mb1  = (const float*)d_in[2];
  const float* mbn1 = (const float*)d_in[3];
  const float* mw2  = (const float*)d_in[4];
  const float* mb2  = (const float*)d_in[5];
  const float* mbn2 = (const float*)d_in[6];
  const float* pw1  = (const float*)d_in[7];
  const float* pb1  = (const float*)d_in[8];
  const float* pbn1 = (const float*)d_in[9];
  const float* pw2  = (const float*)d_in[10];
  const float* pb2  = (const float*)d_in[11];
  const float* pbn2 = (const float*)d_in[12];
  const float* rw1  = (const float*)d_in[13];
  const float* rb1  = (const float*)d_in[14];
  const float* rbn1 = (const float*)d_in[15];
  const float* rw2  = (const float*)d_in[16];
  const float* rb2  = (const float*)d_in[17];
  const float* rbn2 = (const float*)d_in[18];
  const float* lw1  = (const float*)d_in[19];
  const float* lb1  = (const float*)d_in[20];
  const float* lng  = (const float*)d_in[21];
  const float* lnb  = (const float*)d_in[22];
  const float* lw2  = (const float*)d_in[23];
  const float* lb2  = (const float*)d_in[24];

  float* ws = (float*)d_ws;
  float* out = (float*)d_out;

  float* fc    = ws + OFF_FC;
  float* mlog  = ws + OFF_MLOG;
  float* phb   = ws + OFF_PH;
  float* rsum  = ws + OFF_RSUM;
  float* rcnt  = ws + OFF_RCNT;
  float* as1   = ws + OFF_AS1;
  float* as2   = ws + OFF_AS2;
  float* acnt  = ws + OFF_ACNT;
  float* mpool = ws + OFF_MPOOL;
  float* ppool = ws + OFF_PPOOL;
  float* rfb   = ws + OFF_RF;
  float* par   = ws + OFF_PAR;
  unsigned short* wbm  = (unsigned short*)(ws + OFF_WBM);
  unsigned short* wbp  = (unsigned short*)(ws + OFF_WBP);
  unsigned short* w1bm = (unsigned short*)(ws + OFF_W1BM);
  unsigned short* w1bp = (unsigned short*)(ws + OFF_W1BP);

  // zero the accumulator region (rsum..ppool = 3880 floats)
  hipMemsetAsync(rsum, 0, 3880 * sizeof(float), stream);

  prep_kernel<<<193, 256, 0, stream>>>(mw1, pw1, mw2, pw2, mb1, mbn1, mb2, mbn2,
                                       pb1, pbn1, pb2, pbn2, rb1, rbn1, rb2, rbn2,
                                       par, wbm, wbp, w1bm, w1bp);
  row_fft<<<12288, 256, 0, stream>>>(x, fc);
  col_fft_stats<<<dim3(129, 3, 16), 256, 0, stream>>>(fc, mlog, phb, rsum, rcnt,
                                                      as1, as2, acnt);
  conv_mfma<64><<<dim3(16, 16, 16), 256, 0, stream>>>(
      mlog, w1bm, wbm, par + 0, par + 64, par + 128, par + 192, mpool);
  conv_mfma<32><<<dim3(16, 16, 16), 256, 0, stream>>>(
      phb, w1bp, wbp, par + 256, par + 288, par + 320, par + 352, ppool);
  radial_conv<<<16, 128, 0, stream>>>(rsum, rcnt, rw1, rw2, par + 384, par + 416,
                                      par + 448, par + 480, rfb);
  final_mlp<<<16, 256, 0, stream>>>(mpool, ppool, rfb, as1, as2, acnt, lw1, lb1,
                                    lng, lnb, lw2, lb2, out);
}

// Round 4
// 603.118 us; speedup vs baseline: 3.1747x; 1.0565x over previous
//
#include <hip/hip_runtime.h>
#include <math.h>

#define PI_F 3.14159274101257324f   // float(np.pi)

typedef __attribute__((ext_vector_type(8))) short bf16x8;   // 4 VGPRs
typedef __attribute__((ext_vector_type(4))) float f32x4;

// ---------------- workspace layout (float offsets) ----------------
static const size_t OFF_FC    = 0;                    // row-FFT complex out [B*C*256][129]*2
static const size_t OFF_MLOG  = 3170304;              // [B,C,256,129]
static const size_t OFF_PH    = 4755456;              // [B,C,256,129]
static const size_t OFF_RSUM  = 9486336;              // [B,C,32]
static const size_t OFF_RCNT  = OFF_RSUM + 1536;      // [32]
static const size_t OFF_AS1   = OFF_RCNT + 32;        // [B,C,8]
static const size_t OFF_AS2   = OFF_AS1 + 384;        // [B,C,8]
static const size_t OFF_ACNT  = OFF_AS2 + 384;        // [8]
static const size_t OFF_MPOOL = OFF_ACNT + 8;         // [B,64]
static const size_t OFF_PPOOL = OFF_MPOOL + 1024;     // [B,32]
static const size_t OFF_RF    = OFF_PPOOL + 512;      // [B,32]
static const size_t OFF_PAR   = OFF_RF + 512;         // 512 folded BN params
static const size_t OFF_WBM   = OFF_PAR + 512;        // 18432 floats: mag conv2 w [9][64][64] bf16
static const size_t OFF_WBP   = OFF_WBM + 18432;      // 4608 floats: ph conv2 w [9][32][32] bf16
static const size_t OFF_W1BM  = OFF_WBP + 4608;       // 1024 floats: mag conv1 w [64][32] bf16
static const size_t OFF_W1BP  = OFF_W1BM + 1024;      // 512 floats:  ph conv1 w [32][32] bf16
// param sub-offsets: sm1 0, tm1 64, sm2 128, tm2 192, sp1 256, tp1 288, sp2 320, tp2 352,
//                    sr1 384, tr1 416, sr2 448, tr2 480

__device__ __forceinline__ float fix_nan(float v, float pinf, float ninf) {
  if (isnan(v)) return 0.f;
  if (isinf(v)) return v > 0.f ? pinf : ninf;
  return v;
}

__device__ __forceinline__ unsigned short f2bf(float f) {
  unsigned u = __float_as_uint(f);
  unsigned r = (u + 0x7FFFu + ((u >> 16) & 1u)) >> 16;   // RNE (finite values only)
  return (unsigned short)r;
}

// ---------------- prep: fold BN, build bf16 weight layouts ----------------
__device__ __forceinline__ void fold_bn(const float* bn, int C, int c, float cb,
                                        float* s, float* t) {
  float g = bn[c], b = bn[C + c], m = bn[2 * C + c], v = bn[3 * C + c];
  float sc = g / sqrtf(v + 1e-5f);
  *s = sc;
  *t = b + (cb - m) * sc;
}

__global__ __launch_bounds__(256) void prep_kernel(
    const float* __restrict__ mw1, const float* __restrict__ pw1,
    const float* __restrict__ mw2, const float* __restrict__ pw2,
    const float* __restrict__ mb1, const float* __restrict__ mbn1,
    const float* __restrict__ mb2, const float* __restrict__ mbn2,
    const float* __restrict__ pb1, const float* __restrict__ pbn1,
    const float* __restrict__ pb2, const float* __restrict__ pbn2,
    const float* __restrict__ rb1, const float* __restrict__ rbn1,
    const float* __restrict__ rb2, const float* __restrict__ rbn2,
    float* __restrict__ par, unsigned short* __restrict__ wbm,
    unsigned short* __restrict__ wbp, unsigned short* __restrict__ w1bm,
    unsigned short* __restrict__ w1bp) {
  int idx = blockIdx.x * 256 + threadIdx.x;
  if (idx < 36864) {
    int pos = idx / 4096, rem = idx % 4096;
    int oc = rem >> 6, ci = rem & 63;
    wbm[idx] = f2bf(mw2[(oc * 64 + ci) * 9 + pos]);
  } else if (idx < 46080) {
    int i = idx - 36864;
    int pos = i / 1024, rem = i % 1024;
    int oc = rem >> 5, ci = rem & 31;
    wbp[i] = f2bf(pw2[(oc * 32 + ci) * 9 + pos]);
  } else if (idx < 46336) {
    int i = idx - 46080;  // 0..255
    float s, t;
    if (i < 64)       { fold_bn(mbn1, 64, i, mb1[i], &s, &t);          par[i] = s;       par[64 + i] = t; }
    else if (i < 128) { int c = i - 64;  fold_bn(mbn2, 64, c, mb2[c], &s, &t); par[128 + c] = s; par[192 + c] = t; }
    else if (i < 160) { int c = i - 128; fold_bn(pbn1, 32, c, pb1[c], &s, &t); par[256 + c] = s; par[288 + c] = t; }
    else if (i < 192) { int c = i - 160; fold_bn(pbn2, 32, c, pb2[c], &s, &t); par[320 + c] = s; par[352 + c] = t; }
    else if (i < 224) { int c = i - 192; fold_bn(rbn1, 32, c, rb1[c], &s, &t); par[384 + c] = s; par[416 + c] = t; }
    else              { int c = i - 224; fold_bn(rbn2, 32, c, rb2[c], &s, &t); par[448 + c] = s; par[480 + c] = t; }
  } else if (idx < 48384) {
    int i = idx - 46336;                 // conv1 mag weights [oc][k], k = c*9+dy*3+dx, pad 27..31 = 0
    int oc = i >> 5, k = i & 31;
    w1bm[i] = (k < 27) ? f2bf(mw1[oc * 27 + k]) : (unsigned short)0;
  } else if (idx < 49408) {
    int i = idx - 48384;
    int oc = i >> 5, k = i & 31;
    w1bp[i] = (k < 27) ? f2bf(pw1[oc * 27 + k]) : (unsigned short)0;
  }
}

// ---------------- row rFFT (along W): x[.,256] -> complex [.,129] ----------------
// Parity trick: thread kp<128 accumulates even-w and odd-w partial sums with the
// same twiddles; F_kp = Se+So, F_{kp+128} = Se-So (only kp=0's needed: k=128).
// 2 rows per block, all 256 threads active.
__global__ __launch_bounds__(256) void row_fft(const float* __restrict__ x,
                                               float* __restrict__ Fc) {
  const int blk = blockIdx.x;  // 6144 blocks, rows blk*2 + (tid>>7)
  const int tid = threadIdx.x;
  const int half = tid >> 7, kp = tid & 127;
  __shared__ float xr[2][256];
  __shared__ float2 tw[256];
  for (int i = tid; i < 512; i += 256) {
    int rw = i >> 8, w = i & 255;
    float v = x[((size_t)blk * 2 + rw) * 256 + w];
    xr[rw][w] = fminf(fmaxf(v, -10.f), 10.f);
  }
  float sn, cs;
  sincosf((float)(6.283185307179586 / 256.0) * (float)tid, &sn, &cs);
  tw[tid] = make_float2(cs, sn);
  __syncthreads();
  float are = 0.f, aie = 0.f, aro = 0.f, aio = 0.f;
  int t = 0;
  const int kp2 = 2 * kp;
#pragma unroll 4
  for (int w = 0; w < 256; w += 2) {
    float2 t0 = tw[t];
    float2 t1 = tw[(t + kp) & 255];
    float x0 = xr[half][w], x1 = xr[half][w + 1];
    are = fmaf(x0, t0.x, are);
    aie = fmaf(x0, t0.y, aie);
    aro = fmaf(x1, t1.x, aro);
    aio = fmaf(x1, t1.y, aio);
    t = (t + kp2) & 255;
  }
  float2* o = (float2*)Fc;
  size_t rowb = (size_t)(blk * 2 + half) * 129;
  o[rowb + kp] = make_float2(are + aro, -(aie + aio));
  if (kp == 0) o[rowb + 128] = make_float2(are - aro, -(aie - aio));
}

// ---------------- column DFT (along H) + mag/phase + radial/azimuth stats ----------------
__global__ __launch_bounds__(256) void col_fft_stats(
    const float* __restrict__ Fc, float* __restrict__ mlog, float* __restrict__ ph,
    float* __restrict__ rsum, float* __restrict__ rcnt, float* __restrict__ as1,
    float* __restrict__ as2, float* __restrict__ acnt) {
  const int k = blockIdx.x, c = blockIdx.y, b = blockIdx.z;
  const int bc = b * 3 + c;
  const int tid = threadIdx.x;  // = output row j
  __shared__ float2 col[256];
  __shared__ float2 tw[256];
  __shared__ float l_rs[32], l_rc[32];
  __shared__ float l_s1[8], l_s2[8], l_ac[8];
  if (tid < 32) { l_rs[tid] = 0.f; l_rc[tid] = 0.f; }
  if (tid < 8)  { l_s1[tid] = 0.f; l_s2[tid] = 0.f; l_ac[tid] = 0.f; }
  const float2* fc = (const float2*)Fc;
  col[tid] = fc[((size_t)bc * 256 + tid) * 129 + k];
  float sn, cs;
  sincosf((float)(6.283185307179586 / 256.0) * (float)tid, &sn, &cs);
  tw[tid] = make_float2(cs, sn);
  __syncthreads();
  float gr = 0.f, gi = 0.f;
  int t = 0;
#pragma unroll 4
  for (int h = 0; h < 256; ++h) {
    float2 v = col[h];
    float2 w = tw[t];
    gr = fmaf(v.x, w.x, gr);
    gr = fmaf(v.y, w.y, gr);
    gi = fmaf(v.y, w.x, gi);
    gi = fmaf(v.x, -w.y, gi);
    t = (t + tid) & 255;
  }
  float mag = sqrtf(gr * gr + gi * gi);
  mag = fminf(fmaxf(mag, 1e-8f), 1e6f);
  float ml = fminf(fmaxf(log1pf(mag), -20.f), 20.f);
  float p = fminf(fmaxf(atan2f(gi, gr) / PI_F, -1.f), 1.f);
  mlog[((size_t)bc * 256 + tid) * 129 + k] = ml;
  ph[((size_t)bc * 256 + tid) * 129 + k] = p;
  // bins (bit-exact fp32 replication of the reference index math)
  float fy = (float)(tid < 128 ? tid : tid - 256) * (1.0f / 256.0f);
  float fx = (float)k * (1.0f / 256.0f);
  float rad = sqrtf(fx * fx + fy * fy);
  float denom = sqrtf(0.5f) + 1e-8f;
  int rb = (int)((rad / denom) * 31.0f);
  rb = rb < 0 ? 0 : (rb > 31 ? 31 : rb);
  float ang = atan2f(fy, fx + 1e-8f);
  int ab = (int)((ang + PI_F) / (2.0f * PI_F) * 8.0f);
  ab = ab < 0 ? 0 : (ab > 7 ? 7 : ab);
  atomicAdd(&l_rs[rb], mag);
  atomicAdd(&l_s1[ab], mag);
  atomicAdd(&l_s2[ab], mag * mag);
  if (bc == 0) {
    atomicAdd(&l_rc[rb], 1.0f);
    atomicAdd(&l_ac[ab], 1.0f);
  }
  __syncthreads();
  if (tid < 32) {
    atomicAdd(&rsum[bc * 32 + tid], l_rs[tid]);
    if (bc == 0) atomicAdd(&rcnt[tid], l_rc[tid]);
  } else if (tid < 40) {
    int a = tid - 32;
    atomicAdd(&as1[bc * 8 + a], l_s1[a]);
    atomicAdd(&as2[bc * 8 + a], l_s2[a]);
    if (bc == 0) atomicAdd(&acnt[a], l_ac[a]);
  }
}

// ---------------- fused upsample -> conv1(MFMA) -> conv2(MFMA) -> pool ----------------
// 16x16 spatial tile, 4 waves. conv2 B-fragments are register-prefetched with
// distance-2 software pipelining over 18 (kx,ks,ky) granules; granules 0-1 load
// before the conv1 phase (latency hidden under conv1 compute).
template <int C2>
__global__ __launch_bounds__(256, (C2 == 64 ? 2 : 3)) void conv_mfma(
    const float* __restrict__ src,           // [B,3,256,129] spectral plane
    const unsigned short* __restrict__ w1b,  // [C2][32] bf16 conv1 weights
    const unsigned short* __restrict__ wB,   // [9][C2][C2] bf16 conv2 [pos][oc][ci]
    const float* __restrict__ s1, const float* __restrict__ t1,
    const float* __restrict__ s2, const float* __restrict__ t2,
    float* __restrict__ pool) {
  constexpr int ST = C2 + 8;        // f1 row stride in bf16 elems (16B-aligned)
  constexpr int NT = C2 / 16;       // N tiles (oc)
  constexpr int KS = C2 / 32;       // conv2 K steps per kernel position
  constexpr int G = 3 * KS * 3;     // granules: (kx, ks, ky)

  __shared__ float s_in[3][20][20];
  __shared__ float s_sc1[C2], s_sh1[C2];
  __shared__ __align__(16) unsigned short s_f1[324 * ST];
  __shared__ float s_pool[C2];

  const int tid = threadIdx.x;
  const int b = blockIdx.z;
  const int tx0 = blockIdx.x * 16, ty0 = blockIdx.y * 16;
  const int lane = tid & 63, wv = tid >> 6;
  const int ln = lane & 15, q = lane >> 4;

  // stage input tile (halo 2) with fused bilinear W-upsample (129 -> 256)
  for (int idx = tid; idx < 1200; idx += 256) {
    int c = idx / 400, r = idx % 400, iy = r / 20, ix = r % 20;
    int gy = ty0 - 2 + iy, gx = tx0 - 2 + ix;
    float v = 0.f;
    if ((unsigned)gy < 256u && (unsigned)gx < 256u) {
      float srcx = ((float)gx + 0.5f) * (129.0f / 256.0f) - 0.5f;
      float fl = floorf(srcx);
      float w = srcx - fl;
      int x0 = (int)fl, x1 = x0 + 1;
      x0 = x0 < 0 ? 0 : x0;
      x1 = x1 > 128 ? 128 : x1;
      const float* rowp = src + ((size_t)(b * 3 + c) * 256 + gy) * 129;
      v = rowp[x0] * (1.f - w) + rowp[x1] * w;
    }
    s_in[c][iy][ix] = v;
  }
  if (tid < C2) { s_sc1[tid] = s1[tid]; s_sh1[tid] = t1[tid]; s_pool[tid] = 0.f; }

  // conv1 B-fragments (registers; B[k][n]: n=lane&15 -> oc, k=q*8+j contiguous)
  bf16x8 b1[NT];
#pragma unroll
  for (int nt = 0; nt < NT; ++nt)
    b1[nt] = *(const bf16x8*)&w1b[(nt * 16 + ln) * 32 + q * 8];

  // ---- conv2 B prefetch: rotating 3-deep register buffer over granules ----
  bf16x8 Bb[3][NT];
#pragma unroll
  for (int pg = 0; pg < 2; ++pg) {
    const int kx = pg / (KS * 3), ks = (pg / 3) % KS, ky = pg % 3;
#pragma unroll
    for (int nt = 0; nt < NT; ++nt)
      Bb[pg][nt] = *(const bf16x8*)&wB[((size_t)(ky * 3 + kx) * C2 + nt * 16 + ln) * C2 + ks * 32 + q * 8];
  }

  __syncthreads();

  // ---- phase 1: conv1 via MFMA over 18x18 halo (padded to 336 px = 21 m-tiles) ----
  // Out-of-image pixels forced to TRUE ZERO in s_f1 (conv2 pads post-activation feat).
  const float* sp = &s_in[0][0][0];
  int koff[8];
#pragma unroll
  for (int j = 0; j < 8; ++j) {
    int k = q * 8 + j;  // k = c*9 + dy*3 + dx
    if (k < 27) {
      int c = k / 9, rr = k - c * 9, dy = rr / 3, dx = rr - dy * 3;
      koff[j] = (c * 20 + dy) * 20 + dx;
    } else koff[j] = -1;
  }
  for (int mt = wv; mt < 21; mt += 4) {
    int p = mt * 16 + ln;
    int pc = p < 324 ? p : 0;          // dummy pixel for pad rows (results discarded)
    int py = pc / 18, px = pc - py * 18;
    int pix = py * 20 + px;
    bf16x8 af;
#pragma unroll
    for (int j = 0; j < 8; ++j) {
      float v = (koff[j] >= 0) ? sp[koff[j] + pix] : 0.f;
      af[j] = (short)f2bf(v);
    }
    f32x4 c1[NT];
#pragma unroll
    for (int nt = 0; nt < NT; ++nt)
      c1[nt] = __builtin_amdgcn_mfma_f32_16x16x32_bf16(
          af, b1[nt], (f32x4){0.f, 0.f, 0.f, 0.f}, 0, 0, 0);
    // write back: pixel = mt*16 + q*4 + r, oc = nt*16 + ln (C layout: col=lane&15)
#pragma unroll
    for (int r = 0; r < 4; ++r) {
      int pe = mt * 16 + q * 4 + r;
      if (pe < 324) {
        int ey = pe / 18, ex = pe - ey * 18;
        int gy = ty0 - 1 + ey, gx = tx0 - 1 + ex;
        bool inim = ((unsigned)gy < 256u) && ((unsigned)gx < 256u);
#pragma unroll
        for (int nt = 0; nt < NT; ++nt) {
          int oc = nt * 16 + ln;
          float v = inim ? fmaxf(fmaf(c1[nt][r], s_sc1[oc], s_sh1[oc]), 0.f) : 0.f;
          s_f1[pe * ST + oc] = f2bf(v);
        }
      }
    }
  }
  __syncthreads();

  // ---- phase 2: conv2 implicit GEMM, register-pipelined B, a[6] hoisted per (kx,ks) ----
  f32x4 acc[4][NT];
#pragma unroll
  for (int mi = 0; mi < 4; ++mi)
#pragma unroll
    for (int nt = 0; nt < NT; ++nt)
      acc[mi][nt] = (f32x4){0.f, 0.f, 0.f, 0.f};

  const int mt0 = wv * 4;
  bf16x8 a[6];
#pragma unroll
  for (int g = 0; g < G; ++g) {
    const int kx = g / (KS * 3), ks = (g / 3) % KS, ky = g % 3;
    if (ky == 0) {
#pragma unroll
      for (int rr = 0; rr < 6; ++rr)
        a[rr] = *(const bf16x8*)&s_f1[((mt0 + rr) * 18 + ln + kx) * ST + ks * 32 + q * 8];
    }
    if (g + 2 < G) {
      const int pg = g + 2;
      const int pkx = pg / (KS * 3), pks = (pg / 3) % KS, pky = pg % 3;
#pragma unroll
      for (int nt = 0; nt < NT; ++nt)
        Bb[pg % 3][nt] = *(const bf16x8*)&wB[((size_t)(pky * 3 + pkx) * C2 + nt * 16 + ln) * C2 + pks * 32 + q * 8];
    }
#pragma unroll
    for (int mi = 0; mi < 4; ++mi)
#pragma unroll
      for (int nt = 0; nt < NT; ++nt)
        acc[mi][nt] = __builtin_amdgcn_mfma_f32_16x16x32_bf16(
            a[mi + ky], Bb[g % 3][nt], acc[mi][nt], 0, 0, 0);
  }

  // epilogue: BN+ReLU, pool partials. D layout: col(oc)=lane&15, rows = quad*4+reg.
#pragma unroll
  for (int nt = 0; nt < NT; ++nt) {
    const int oc = nt * 16 + ln;
    const float sc = s2[oc], sh = t2[oc];
    float v = 0.f;
#pragma unroll
    for (int mi = 0; mi < 4; ++mi)
#pragma unroll
      for (int r = 0; r < 4; ++r)
        v += fmaxf(fmaf(acc[mi][nt][r], sc, sh), 0.f);
    v += __shfl_xor(v, 16);
    v += __shfl_xor(v, 32);
    if (q == 0) atomicAdd(&s_pool[oc], v);
  }
  __syncthreads();
  if (tid < C2) atomicAdd(&pool[b * C2 + tid], s_pool[tid]);
}

// ---------------- radial 1d conv branch ----------------
__global__ __launch_bounds__(128) void radial_conv(
    const float* __restrict__ rsum, const float* __restrict__ rcnt,
    const float* __restrict__ rw1, const float* __restrict__ rw2,
    const float* __restrict__ sr1, const float* __restrict__ tr1,
    const float* __restrict__ sr2, const float* __restrict__ tr2,
    float* __restrict__ rf) {
  int b = blockIdx.x, t = threadIdx.x;
  __shared__ float rad[3][32];
  __shared__ float f1[32][32];
  __shared__ float f2[32][32];
  if (t < 96) {
    int c = t / 32, i = t % 32;
    float cnt = fmaxf(rcnt[i], 1.0f);
    float v = rsum[(b * 3 + c) * 32 + i] / cnt;
    rad[c][i] = fminf(fmaxf(v, 0.f), 1e6f);
  }
  __syncthreads();
  for (int idx = t; idx < 1024; idx += 128) {
    int oc = idx >> 5, i = idx & 31;
    float a = 0.f;
    for (int c = 0; c < 3; ++c)
#pragma unroll
      for (int d = 0; d < 3; ++d) {
        int ii = i + d - 1;
        if (ii >= 0 && ii < 32) a = fmaf(rad[c][ii], rw1[(oc * 3 + c) * 3 + d], a);
      }
    f1[oc][i] = fmaxf(fmaf(a, sr1[oc], tr1[oc]), 0.f);
  }
  __syncthreads();
  for (int idx = t; idx < 1024; idx += 128) {
    int oc = idx >> 5, i = idx & 31;
    float a = 0.f;
    for (int c = 0; c < 32; ++c)
#pragma unroll
      for (int d = 0; d < 3; ++d) {
        int ii = i + d - 1;
        if (ii >= 0 && ii < 32) a = fmaf(f1[c][ii], rw2[(oc * 32 + c) * 3 + d], a);
      }
    f2[oc][i] = fmaxf(fmaf(a, sr2[oc], tr2[oc]), 0.f);
  }
  __syncthreads();
  if (t < 32) {
    float s = 0.f;
    for (int i = 0; i < 32; ++i) s += f2[t][i];
    rf[b * 32 + t] = s * (1.0f / 32.0f);
  }
}

// ---------------- final: comb assembly, linear, layernorm, relu, linear ----------------
__global__ __launch_bounds__(256) void final_mlp(
    const float* __restrict__ mpool, const float* __restrict__ ppool,
    const float* __restrict__ rf, const float* __restrict__ as1,
    const float* __restrict__ as2, const float* __restrict__ acnt,
    const float* __restrict__ lw1, const float* __restrict__ lb1,
    const float* __restrict__ lng, const float* __restrict__ lnb,
    const float* __restrict__ lw2, const float* __restrict__ lb2,
    float* __restrict__ out) {
  int b = blockIdx.x, t = threadIdx.x;
  __shared__ float comb[176];
  __shared__ float red[256];
  __shared__ float hrelu[256];
  __shared__ float s_mu, s_var;
  if (t < 64) comb[t] = fix_nan(mpool[b * 64 + t] * (1.0f / 65536.0f), 1e4f, -1e4f);
  else if (t < 96) comb[t] = fix_nan(ppool[b * 32 + t - 64] * (1.0f / 65536.0f), 1e4f, -1e4f);
  else if (t < 128) comb[t] = fix_nan(rf[b * 32 + t - 96], 1e4f, -1e4f);
  else if (t < 176) {
    int j = t - 128;
    int a = j / 6, r = j % 6, m = r / 3, c = r % 3;
    float cnt = acnt[a];
    float v = 0.f;  // empty sector -> NaN -> nan_to_num -> 0
    if (cnt > 0.f) {
      float s1v = as1[(b * 3 + c) * 8 + a], s2v = as2[(b * 3 + c) * 8 + a];
      float mean = s1v / cnt;
      if (m == 0)
        v = mean;
      else {
        float var = (s2v - cnt * mean * mean) / fmaxf(cnt - 1.f, 1.f);
        v = sqrtf(fmaxf(var, 0.f));
      }
    }
    comb[t] = fix_nan(v, 1e4f, -1e4f);
  }
  __syncthreads();
  float h = lb1[t];
  const float* wr = lw1 + t * 176;
#pragma unroll 8
  for (int j = 0; j < 176; ++j) h = fmaf(comb[j], wr[j], h);
  red[t] = h;
  __syncthreads();
  for (int s = 128; s > 0; s >>= 1) {
    if (t < s) red[t] += red[t + s];
    __syncthreads();
  }
  if (t == 0) s_mu = red[0] * (1.0f / 256.0f);
  __syncthreads();
  float mu = s_mu;
  float d = h - mu;
  red[t] = d * d;
  __syncthreads();
  for (int s = 128; s > 0; s >>= 1) {
    if (t < s) red[t] += red[t + s];
    __syncthreads();
  }
  if (t == 0) s_var = red[0] * (1.0f / 256.0f);
  __syncthreads();
  float hn = d / sqrtf(s_var + 1e-5f) * lng[t] + lnb[t];
  hrelu[t] = fmaxf(hn, 0.f);
  __syncthreads();
  if (t < 128) {
    float o = lb2[t];
    const float* w2r = lw2 + t * 256;
#pragma unroll 8
    for (int j = 0; j < 256; ++j) o = fmaf(hrelu[j], w2r[j], o);
    o = fminf(fmaxf(o, -100.f), 100.f);
    out[b * 128 + t] = fix_nan(o, 100.f, -100.f);
  }
}

// ---------------- host launcher ----------------
extern "C" void kernel_launch(void* const* d_in, const int* in_sizes, int n_in,
                              void* d_out, int out_size, void* d_ws, size_t ws_size,
                              hipStream_t stream) {
  const float* x    = (const float*)d_in[0];
  const float* mw1  = (const float*)d_in[1];
  const float* mb1  = (const float*)d_in[2];
  const float* mbn1 = (const float*)d_in[3];
  const float* mw2  = (const float*)d_in[4];
  const float* mb2  = (const float*)d_in[5];
  const float* mbn2 = (const float*)d_in[6];
  const float* pw1  = (const float*)d_in[7];
  const float* pb1  = (const float*)d_in[8];
  const float* pbn1 = (const float*)d_in[9];
  const float* pw2  = (const float*)d_in[10];
  const float* pb2  = (const float*)d_in[11];
  const float* pbn2 = (const float*)d_in[12];
  const float* rw1  = (const float*)d_in[13];
  const float* rb1  = (const float*)d_in[14];
  const float* rbn1 = (const float*)d_in[15];
  const float* rw2  = (const float*)d_in[16];
  const float* rb2  = (const float*)d_in[17];
  const float* rbn2 = (const float*)d_in[18];
  const float* lw1  = (const float*)d_in[19];
  const float* lb1  = (const float*)d_in[20];
  const float* lng  = (const float*)d_in[21];
  const float* lnb  = (const float*)d_in[22];
  const float* lw2  = (const float*)d_in[23];
  const float* lb2  = (const float*)d_in[24];

  float* ws = (float*)d_ws;
  float* out = (float*)d_out;

  float* fc    = ws + OFF_FC;
  float* mlog  = ws + OFF_MLOG;
  float* phb   = ws + OFF_PH;
  float* rsum  = ws + OFF_RSUM;
  float* rcnt  = ws + OFF_RCNT;
  float* as1   = ws + OFF_AS1;
  float* as2   = ws + OFF_AS2;
  float* acnt  = ws + OFF_ACNT;
  float* mpool = ws + OFF_MPOOL;
  float* ppool = ws + OFF_PPOOL;
  float* rfb   = ws + OFF_RF;
  float* par   = ws + OFF_PAR;
  unsigned short* wbm  = (unsigned short*)(ws + OFF_WBM);
  unsigned short* wbp  = (unsigned short*)(ws + OFF_WBP);
  unsigned short* w1bm = (unsigned short*)(ws + OFF_W1BM);
  unsigned short* w1bp = (unsigned short*)(ws + OFF_W1BP);

  // zero the accumulator region (rsum..ppool = 3880 floats)
  hipMemsetAsync(rsum, 0, 3880 * sizeof(float), stream);

  prep_kernel<<<193, 256, 0, stream>>>(mw1, pw1, mw2, pw2, mb1, mbn1, mb2, mbn2,
                                       pb1, pbn1, pb2, pbn2, rb1, rbn1, rb2, rbn2,
                                       par, wbm, wbp, w1bm, w1bp);
  row_fft<<<6144, 256, 0, stream>>>(x, fc);
  col_fft_stats<<<dim3(129, 3, 16), 256, 0, stream>>>(fc, mlog, phb, rsum, rcnt,
                                                      as1, as2, acnt);
  conv_mfma<64><<<dim3(16, 16, 16), 256, 0, stream>>>(
      mlog, w1bm, wbm, par + 0, par + 64, par + 128, par + 192, mpool);
  conv_mfma<32><<<dim3(16, 16, 16), 256, 0, stream>>>(
      phb, w1bp, wbp, par + 256, par + 288, par + 320, par + 352, ppool);
  radial_conv<<<16, 128, 0, stream>>>(rsum, rcnt, rw1, rw2, par + 384, par + 416,
                                      par + 448, par + 480, rfb);
  final_mlp<<<16, 256, 0, stream>>>(mpool, ppool, rfb, as1, as2, acnt, lw1, lb1,
                                    lng, lnb, lw2, lb2, out);
}

// Round 5
// 563.340 us; speedup vs baseline: 3.3989x; 1.0706x over previous
//
#include <hip/hip_runtime.h>
#include <math.h>

#define PI_F 3.14159274101257324f   // float(np.pi)

typedef __attribute__((ext_vector_type(8))) short bf16x8;   // 4 VGPRs
typedef __attribute__((ext_vector_type(4))) float f32x4;

// ---------------- workspace layout (float offsets) ----------------
static const size_t OFF_FC    = 0;                    // row-FFT complex out [B*C*256][129]*2
static const size_t OFF_MLOG  = 3170304;              // [B,C,256,129]
static const size_t OFF_PH    = 4755456;              // [B,C,256,129]
static const size_t OFF_RSUM  = 9486336;              // [B,C,32]
static const size_t OFF_RCNT  = OFF_RSUM + 1536;      // [32]
static const size_t OFF_AS1   = OFF_RCNT + 32;        // [B,C,8]
static const size_t OFF_AS2   = OFF_AS1 + 384;        // [B,C,8]
static const size_t OFF_ACNT  = OFF_AS2 + 384;        // [8]
static const size_t OFF_MPOOL = OFF_ACNT + 8;         // [B,64]
static const size_t OFF_PPOOL = OFF_MPOOL + 1024;     // [B,32]
static const size_t OFF_RF    = OFF_PPOOL + 512;      // (unused now)
static const size_t OFF_PAR   = OFF_RF + 512;         // 512 folded BN params
static const size_t OFF_WBM   = OFF_PAR + 512;        // 18432 floats: mag conv2 w [9][64][64] bf16
static const size_t OFF_WBP   = OFF_WBM + 18432;      // 4608 floats: ph conv2 w [9][32][32] bf16
static const size_t OFF_W1BM  = OFF_WBP + 4608;       // 1024 floats: mag conv1 w [64][32] bf16
static const size_t OFF_W1BP  = OFF_W1BM + 1024;      // 512 floats:  ph conv1 w [32][32] bf16
// param sub-offsets: sm1 0, tm1 64, sm2 128, tm2 192, sp1 256, tp1 288, sp2 320, tp2 352,
//                    sr1 384, tr1 416, sr2 448, tr2 480

__device__ __forceinline__ float fix_nan(float v, float pinf, float ninf) {
  if (isnan(v)) return 0.f;
  if (isinf(v)) return v > 0.f ? pinf : ninf;
  return v;
}

__device__ __forceinline__ unsigned short f2bf(float f) {
  unsigned u = __float_as_uint(f);
  unsigned r = (u + 0x7FFFu + ((u >> 16) & 1u)) >> 16;   // RNE (finite values only)
  return (unsigned short)r;
}

__device__ __forceinline__ void fold_bn(const float* bn, int C, int c, float cb,
                                        float* s, float* t) {
  float g = bn[c], b = bn[C + c], m = bn[2 * C + c], v = bn[3 * C + c];
  float sc = g / sqrtf(v + 1e-5f);
  *s = sc;
  *t = b + (cb - m) * sc;
}

// ---------------- row rFFT + (fused) prep + ws zeroing ----------------
// blocks 0..6143: row FFT (parity trick, 2 rows/block). block 0 also zeroes the
// accumulator region. blocks 6144..6336: weight/BN prep (one dispatch saved).
__global__ __launch_bounds__(256) void row_fft_prep(
    const float* __restrict__ x, float* __restrict__ Fc, float* __restrict__ zbuf,
    const float* __restrict__ mw1, const float* __restrict__ pw1,
    const float* __restrict__ mw2, const float* __restrict__ pw2,
    const float* __restrict__ mb1, const float* __restrict__ mbn1,
    const float* __restrict__ mb2, const float* __restrict__ mbn2,
    const float* __restrict__ pb1, const float* __restrict__ pbn1,
    const float* __restrict__ pb2, const float* __restrict__ pbn2,
    const float* __restrict__ rb1, const float* __restrict__ rbn1,
    const float* __restrict__ rb2, const float* __restrict__ rbn2,
    float* __restrict__ par, unsigned short* __restrict__ wbm,
    unsigned short* __restrict__ wbp, unsigned short* __restrict__ w1bm,
    unsigned short* __restrict__ w1bp) {
  const int blk = blockIdx.x;
  const int tid = threadIdx.x;
  if (blk >= 6144) {
    int idx = (blk - 6144) * 256 + tid;
    if (idx < 36864) {
      int pos = idx / 4096, rem = idx % 4096;
      int oc = rem >> 6, ci = rem & 63;
      wbm[idx] = f2bf(mw2[(oc * 64 + ci) * 9 + pos]);
    } else if (idx < 46080) {
      int i = idx - 36864;
      int pos = i / 1024, rem = i % 1024;
      int oc = rem >> 5, ci = rem & 31;
      wbp[i] = f2bf(pw2[(oc * 32 + ci) * 9 + pos]);
    } else if (idx < 46336) {
      int i = idx - 46080;  // 0..255
      float s, t;
      if (i < 64)       { fold_bn(mbn1, 64, i, mb1[i], &s, &t);          par[i] = s;       par[64 + i] = t; }
      else if (i < 128) { int c = i - 64;  fold_bn(mbn2, 64, c, mb2[c], &s, &t); par[128 + c] = s; par[192 + c] = t; }
      else if (i < 160) { int c = i - 128; fold_bn(pbn1, 32, c, pb1[c], &s, &t); par[256 + c] = s; par[288 + c] = t; }
      else if (i < 192) { int c = i - 160; fold_bn(pbn2, 32, c, pb2[c], &s, &t); par[320 + c] = s; par[352 + c] = t; }
      else if (i < 224) { int c = i - 192; fold_bn(rbn1, 32, c, rb1[c], &s, &t); par[384 + c] = s; par[416 + c] = t; }
      else              { int c = i - 224; fold_bn(rbn2, 32, c, rb2[c], &s, &t); par[448 + c] = s; par[480 + c] = t; }
    } else if (idx < 48384) {
      int i = idx - 46336;                 // conv1 mag w [oc][k], k=c*9+dy*3+dx, pad->0
      int oc = i >> 5, k = i & 31;
      w1bm[i] = (k < 27) ? f2bf(mw1[oc * 27 + k]) : (unsigned short)0;
    } else if (idx < 49408) {
      int i = idx - 48384;
      int oc = i >> 5, k = i & 31;
      w1bp[i] = (k < 27) ? f2bf(pw1[oc * 27 + k]) : (unsigned short)0;
    }
    return;
  }
  if (blk == 0) {
    for (int i = tid; i < 3880; i += 256) zbuf[i] = 0.f;   // rsum..ppool accumulators
  }
  const int half = tid >> 7, kp = tid & 127;
  __shared__ float xr[2][256];
  __shared__ float2 tw[256];
  for (int i = tid; i < 512; i += 256) {
    int rw = i >> 8, w = i & 255;
    float v = x[((size_t)blk * 2 + rw) * 256 + w];
    xr[rw][w] = fminf(fmaxf(v, -10.f), 10.f);
  }
  float sn, cs;
  sincosf((float)(6.283185307179586 / 256.0) * (float)tid, &sn, &cs);
  tw[tid] = make_float2(cs, sn);
  __syncthreads();
  float are = 0.f, aie = 0.f, aro = 0.f, aio = 0.f;
  int t = 0;
  const int kp2 = 2 * kp;
#pragma unroll 4
  for (int w = 0; w < 256; w += 2) {
    float2 t0 = tw[t];
    float2 t1 = tw[(t + kp) & 255];
    float x0 = xr[half][w], x1 = xr[half][w + 1];
    are = fmaf(x0, t0.x, are);
    aie = fmaf(x0, t0.y, aie);
    aro = fmaf(x1, t1.x, aro);
    aio = fmaf(x1, t1.y, aio);
    t = (t + kp2) & 255;
  }
  float2* o = (float2*)Fc;
  size_t rowb = (size_t)(blk * 2 + half) * 129;
  o[rowb + kp] = make_float2(are + aro, -(aie + aio));
  if (kp == 0) o[rowb + 128] = make_float2(are - aro, -(aie - aio));
}

// ---------------- column DFT (along H) + mag/phase + radial/azimuth stats ----------------
__global__ __launch_bounds__(256) void col_fft_stats(
    const float* __restrict__ Fc, float* __restrict__ mlog, float* __restrict__ ph,
    float* __restrict__ rsum, float* __restrict__ rcnt, float* __restrict__ as1,
    float* __restrict__ as2, float* __restrict__ acnt) {
  const int k = blockIdx.x, c = blockIdx.y, b = blockIdx.z;
  const int bc = b * 3 + c;
  const int tid = threadIdx.x;  // = output row j
  const int wv = tid >> 6;
  __shared__ float2 col[256];
  __shared__ float2 tw[256];
  __shared__ float l_rs[4][32], l_rc[4][32];
  __shared__ float l_s1[4][8], l_s2[4][8], l_ac[4][8];
  for (int i = tid; i < 128; i += 256) { l_rs[i >> 5][i & 31] = 0.f; l_rc[i >> 5][i & 31] = 0.f; }
  if (tid < 32) { l_s1[tid >> 3][tid & 7] = 0.f; l_s2[tid >> 3][tid & 7] = 0.f; l_ac[tid >> 3][tid & 7] = 0.f; }
  const float2* fc = (const float2*)Fc;
  col[tid] = fc[((size_t)bc * 256 + tid) * 129 + k];
  float sn, cs;
  sincosf((float)(6.283185307179586 / 256.0) * (float)tid, &sn, &cs);
  tw[tid] = make_float2(cs, sn);
  __syncthreads();
  float gr = 0.f, gi = 0.f;
  int t = 0;
#pragma unroll 4
  for (int h = 0; h < 256; ++h) {
    float2 v = col[h];
    float2 w = tw[t];
    gr = fmaf(v.x, w.x, gr);
    gr = fmaf(v.y, w.y, gr);
    gi = fmaf(v.y, w.x, gi);
    gi = fmaf(v.x, -w.y, gi);
    t = (t + tid) & 255;
  }
  float mag = sqrtf(gr * gr + gi * gi);
  mag = fminf(fmaxf(mag, 1e-8f), 1e6f);
  float ml = fminf(fmaxf(log1pf(mag), -20.f), 20.f);
  float p = fminf(fmaxf(atan2f(gi, gr) / PI_F, -1.f), 1.f);
  mlog[((size_t)bc * 256 + tid) * 129 + k] = ml;
  ph[((size_t)bc * 256 + tid) * 129 + k] = p;
  // bins (bit-exact fp32 replication of the reference index math)
  float fy = (float)(tid < 128 ? tid : tid - 256) * (1.0f / 256.0f);
  float fx = (float)k * (1.0f / 256.0f);
  float rad = sqrtf(fx * fx + fy * fy);
  float denom = sqrtf(0.5f) + 1e-8f;
  int rb = (int)((rad / denom) * 31.0f);
  rb = rb < 0 ? 0 : (rb > 31 ? 31 : rb);
  float ang = atan2f(fy, fx + 1e-8f);
  int ab = (int)((ang + PI_F) / (2.0f * PI_F) * 8.0f);
  ab = ab < 0 ? 0 : (ab > 7 ? 7 : ab);
  atomicAdd(&l_rs[wv][rb], mag);
  atomicAdd(&l_s1[wv][ab], mag);
  atomicAdd(&l_s2[wv][ab], mag * mag);
  if (bc == 0) {
    atomicAdd(&l_rc[wv][rb], 1.0f);
    atomicAdd(&l_ac[wv][ab], 1.0f);
  }
  __syncthreads();
  if (tid < 32) {
    float s = l_rs[0][tid] + l_rs[1][tid] + l_rs[2][tid] + l_rs[3][tid];
    atomicAdd(&rsum[bc * 32 + tid], s);
    if (bc == 0) {
      float cv = l_rc[0][tid] + l_rc[1][tid] + l_rc[2][tid] + l_rc[3][tid];
      atomicAdd(&rcnt[tid], cv);
    }
  } else if (tid < 40) {
    int a = tid - 32;
    atomicAdd(&as1[bc * 8 + a], l_s1[0][a] + l_s1[1][a] + l_s1[2][a] + l_s1[3][a]);
    atomicAdd(&as2[bc * 8 + a], l_s2[0][a] + l_s2[1][a] + l_s2[2][a] + l_s2[3][a]);
    if (bc == 0) atomicAdd(&acnt[a], l_ac[0][a] + l_ac[1][a] + l_ac[2][a] + l_ac[3][a]);
  }
}

// ---------------- fused upsample -> conv1(MFMA) -> conv2(MFMA) -> pool ----------------
// 16x16 spatial tile, 4 waves. Wave = (oc-group ntg, row-half). conv2 B-fragments:
// C2=64 rolling distance-1 register prefetch (first granule issued before conv1);
// C2=32 all 9 frags preloaded. conv1 operand-swapped so D rows = contiguous oc
// -> packed 8B LDS writebacks.
template <int C2>
__global__ __launch_bounds__(256, 2) void conv_mfma(
    const float* __restrict__ src,           // [B,3,256,129] spectral plane
    const unsigned short* __restrict__ w1b,  // [C2][32] bf16 conv1 weights
    const unsigned short* __restrict__ wB,   // [9][C2][C2] bf16 conv2 [pos][oc][ci]
    const float* __restrict__ s1, const float* __restrict__ t1,
    const float* __restrict__ s2, const float* __restrict__ t2,
    float* __restrict__ pool) {
  constexpr int ST = C2 + 8;                 // f1 row stride (16B-aligned rows)
  constexpr int NT = C2 / 16;                // total oc tiles
  constexpr int WNT = (C2 == 64) ? 2 : 1;    // oc tiles per wave
  constexpr int KS = C2 / 32;                // conv2 K steps per kx
  constexpr int NG = 3 * KS;                 // (kx,ks) granules

  __shared__ float s_in[3][20][20];
  __shared__ float s_sc1[C2], s_sh1[C2];
  __shared__ __align__(16) unsigned short s_f1[324 * ST];

  const int tid = threadIdx.x;
  const int b = blockIdx.z;
  const int tx0 = blockIdx.x * 16, ty0 = blockIdx.y * 16;
  const int lane = tid & 63, wv = tid >> 6;
  const int ln = lane & 15, q = lane >> 4;
  const int ntg = wv & 1, half = wv >> 1;
  const int ocb0 = ntg * WNT * 16;

  // stage input tile (halo 2) with fused bilinear W-upsample (129 -> 256)
  for (int idx = tid; idx < 1200; idx += 256) {
    int c = idx / 400, r = idx % 400, iy = r / 20, ix = r % 20;
    int gy = ty0 - 2 + iy, gx = tx0 - 2 + ix;
    float v = 0.f;
    if ((unsigned)gy < 256u && (unsigned)gx < 256u) {
      float srcx = ((float)gx + 0.5f) * (129.0f / 256.0f) - 0.5f;
      float fl = floorf(srcx);
      float w = srcx - fl;
      int x0 = (int)fl, x1 = x0 + 1;
      x0 = x0 < 0 ? 0 : x0;
      x1 = x1 > 128 ? 128 : x1;
      const float* rowp = src + ((size_t)(b * 3 + c) * 256 + gy) * 129;
      v = rowp[x0] * (1.f - w) + rowp[x1] * w;
    }
    s_in[c][iy][ix] = v;
  }
  if (tid < C2) { s_sc1[tid] = s1[tid]; s_sh1[tid] = t1[tid]; }

  // conv1 A-side weights (all oc tiles; A[m=oc][k=tap])
  bf16x8 b1[NT];
#pragma unroll
  for (int nt = 0; nt < NT; ++nt)
    b1[nt] = *(const bf16x8*)&w1b[(nt * 16 + ln) * 32 + q * 8];

  // conv2 B prefetch (issued before conv1 so the pipe is warm at conv2 start)
  bf16x8 Bb[2][3 * WNT];     // rolling (C2==64)
  bf16x8 Bw[(C2 == 32) ? 9 : 1];
  if constexpr (C2 == 64) {
#pragma unroll
    for (int ky = 0; ky < 3; ++ky)
#pragma unroll
      for (int w = 0; w < 2; ++w)
        Bb[0][ky * 2 + w] =
            *(const bf16x8*)&wB[((size_t)(ky * 3) * 64 + ocb0 + w * 16 + ln) * 64 + q * 8];
  } else {
#pragma unroll
    for (int kx = 0; kx < 3; ++kx)
#pragma unroll
      for (int ky = 0; ky < 3; ++ky)
        Bw[kx * 3 + ky] =
            *(const bf16x8*)&wB[((size_t)(ky * 3 + kx) * 32 + ocb0 + ln) * 32 + q * 8];
  }

  __syncthreads();

  // BN params for conv1 writeback (oc = nt*16 + q*4 + r)
  float c1sc[NT][4], c1sh[NT][4];
#pragma unroll
  for (int nt = 0; nt < NT; ++nt)
#pragma unroll
    for (int r = 0; r < 4; ++r) {
      c1sc[nt][r] = s_sc1[nt * 16 + q * 4 + r];
      c1sh[nt][r] = s_sh1[nt * 16 + q * 4 + r];
    }

  // ---- phase 1: conv1 via MFMA (D[oc][pixel]); 18x18 halo = 324 px in 21 m-tiles ----
  const float* sp = &s_in[0][0][0];
  int koff[8];
#pragma unroll
  for (int j = 0; j < 8; ++j) {
    int k = q * 8 + j;  // k = c*9 + dy*3 + dx
    if (k < 27) {
      int c = k / 9, rr = k - c * 9, dy = rr / 3, dx = rr - dy * 3;
      koff[j] = (c * 20 + dy) * 20 + dx;
    } else koff[j] = -1;
  }
  for (int mt = wv; mt < 21; mt += 4) {
    int p = mt * 16 + ln;
    int pc = p < 324 ? p : 0;           // dummy pixel for pad lanes (cols discarded)
    int py = pc / 18, px = pc - py * 18;
    int pix = py * 20 + px;
    union { bf16x8 v; unsigned u[4]; } af;
#pragma unroll
    for (int jj = 0; jj < 4; ++jj) {
      float v0 = (koff[2 * jj] >= 0) ? sp[koff[2 * jj] + pix] : 0.f;
      float v1 = (koff[2 * jj + 1] >= 0) ? sp[koff[2 * jj + 1] + pix] : 0.f;
      af.u[jj] = (unsigned)f2bf(v0) | ((unsigned)f2bf(v1) << 16);
    }
    bool inim = false;
    if (p < 324) {
      int gy = ty0 - 1 + py, gx = tx0 - 1 + px;
      inim = ((unsigned)gy < 256u) && ((unsigned)gx < 256u);
    }
#pragma unroll
    for (int nt = 0; nt < NT; ++nt) {
      f32x4 c1 = __builtin_amdgcn_mfma_f32_16x16x32_bf16(
          b1[nt], af.v, (f32x4){0.f, 0.f, 0.f, 0.f}, 0, 0, 0);
      if (p < 324) {
        float v0 = inim ? fmaxf(fmaf(c1[0], c1sc[nt][0], c1sh[nt][0]), 0.f) : 0.f;
        float v1 = inim ? fmaxf(fmaf(c1[1], c1sc[nt][1], c1sh[nt][1]), 0.f) : 0.f;
        float v2 = inim ? fmaxf(fmaf(c1[2], c1sc[nt][2], c1sh[nt][2]), 0.f) : 0.f;
        float v3 = inim ? fmaxf(fmaf(c1[3], c1sc[nt][3], c1sh[nt][3]), 0.f) : 0.f;
        uint2 pk;
        pk.x = (unsigned)f2bf(v0) | ((unsigned)f2bf(v1) << 16);
        pk.y = (unsigned)f2bf(v2) | ((unsigned)f2bf(v3) << 16);
        *(uint2*)&s_f1[p * ST + nt * 16 + q * 4] = pk;  // 8B aligned
      }
    }
  }
  __syncthreads();

  // ---- phase 2: conv2 implicit GEMM; wave = WNT oc-tiles x 8 pixel-rows ----
  f32x4 acc[WNT][8];
#pragma unroll
  for (int w = 0; w < WNT; ++w)
#pragma unroll
    for (int i = 0; i < 8; ++i)
      acc[w][i] = (f32x4){0.f, 0.f, 0.f, 0.f};

  const int rbase = half * 8;
#pragma unroll
  for (int g = 0; g < NG; ++g) {
    const int kx = g / KS, ks = g % KS;
    if constexpr (C2 == 64) {
      if (g + 1 < NG) {
        const int nkx = (g + 1) / KS, nks = (g + 1) % KS;
#pragma unroll
        for (int ky = 0; ky < 3; ++ky)
#pragma unroll
          for (int w = 0; w < 2; ++w)
            Bb[(g + 1) & 1][ky * 2 + w] =
                *(const bf16x8*)&wB[((size_t)(ky * 3 + nkx) * 64 + ocb0 + w * 16 + ln) * 64 +
                                    nks * 32 + q * 8];
      }
    }
    bf16x8 a[10];
#pragma unroll
    for (int rr = 0; rr < 10; ++rr)
      a[rr] = *(const bf16x8*)&s_f1[((rbase + rr) * 18 + ln + kx) * ST + ks * 32 + q * 8];
#pragma unroll
    for (int ky = 0; ky < 3; ++ky)
#pragma unroll
      for (int w = 0; w < WNT; ++w) {
        bf16x8 bf;
        if constexpr (C2 == 64) bf = Bb[g & 1][ky * 2 + w];
        else bf = Bw[kx * 3 + ky];
#pragma unroll
        for (int i = 0; i < 8; ++i)
          acc[w][i] = __builtin_amdgcn_mfma_f32_16x16x32_bf16(a[i + ky], bf, acc[w][i], 0, 0, 0);
      }
  }

  // epilogue: BN+ReLU + pool partial. D: col(ln)=oc, rows=pixel cols (q*4+r).
#pragma unroll
  for (int w = 0; w < WNT; ++w) {
    const int oc = ocb0 + w * 16 + ln;
    const float sc = s2[oc], sh = t2[oc];
    float v = 0.f;
#pragma unroll
    for (int i = 0; i < 8; ++i)
#pragma unroll
      for (int r = 0; r < 4; ++r)
        v += fmaxf(fmaf(acc[w][i][r], sc, sh), 0.f);
    v += __shfl_xor(v, 16);
    v += __shfl_xor(v, 32);
    if (q == 0) atomicAdd(&pool[b * C2 + oc], v);
  }
}

// ---------------- final: radial conv branch + comb + linear/LN/relu/linear ----------------
__global__ __launch_bounds__(256) void final_mlp(
    const float* __restrict__ rsum, const float* __restrict__ rcnt,
    const float* __restrict__ rw1, const float* __restrict__ rw2,
    const float* __restrict__ sr1, const float* __restrict__ tr1,
    const float* __restrict__ sr2, const float* __restrict__ tr2,
    const float* __restrict__ mpool, const float* __restrict__ ppool,
    const float* __restrict__ as1, const float* __restrict__ as2,
    const float* __restrict__ acnt,
    const float* __restrict__ lw1, const float* __restrict__ lb1,
    const float* __restrict__ lng, const float* __restrict__ lnb,
    const float* __restrict__ lw2, const float* __restrict__ lb2,
    float* __restrict__ out) {
  int b = blockIdx.x, t = threadIdx.x;
  __shared__ float rad[3][32];
  __shared__ float rf1[32][32];
  __shared__ float rf2[32][32];
  __shared__ float rfv[32];
  __shared__ float comb[176];
  __shared__ float red[256];
  __shared__ float hrelu[256];
  __shared__ float s_mu, s_var;

  // ---- radial branch ----
  if (t < 96) {
    int c = t / 32, i = t % 32;
    float cnt = fmaxf(rcnt[i], 1.0f);
    float v = rsum[(b * 3 + c) * 32 + i] / cnt;
    rad[c][i] = fminf(fmaxf(v, 0.f), 1e6f);
  }
  __syncthreads();
  for (int idx = t; idx < 1024; idx += 256) {
    int oc = idx >> 5, i = idx & 31;
    float a = 0.f;
    for (int c = 0; c < 3; ++c)
#pragma unroll
      for (int d = 0; d < 3; ++d) {
        int ii = i + d - 1;
        if (ii >= 0 && ii < 32) a = fmaf(rad[c][ii], rw1[(oc * 3 + c) * 3 + d], a);
      }
    rf1[oc][i] = fmaxf(fmaf(a, sr1[oc], tr1[oc]), 0.f);
  }
  __syncthreads();
  for (int idx = t; idx < 1024; idx += 256) {
    int oc = idx >> 5, i = idx & 31;
    float a = 0.f;
    for (int c = 0; c < 32; ++c)
#pragma unroll
      for (int d = 0; d < 3; ++d) {
        int ii = i + d - 1;
        if (ii >= 0 && ii < 32) a = fmaf(rf1[c][ii], rw2[(oc * 32 + c) * 3 + d], a);
      }
    rf2[oc][i] = fmaxf(fmaf(a, sr2[oc], tr2[oc]), 0.f);
  }
  __syncthreads();
  if (t < 32) {
    float s = 0.f;
    for (int i = 0; i < 32; ++i) s += rf2[t][i];
    rfv[t] = s * (1.0f / 32.0f);
  }
  __syncthreads();

  // ---- comb assembly ----
  if (t < 64) comb[t] = fix_nan(mpool[b * 64 + t] * (1.0f / 65536.0f), 1e4f, -1e4f);
  else if (t < 96) comb[t] = fix_nan(ppool[b * 32 + t - 64] * (1.0f / 65536.0f), 1e4f, -1e4f);
  else if (t < 128) comb[t] = fix_nan(rfv[t - 96], 1e4f, -1e4f);
  else if (t < 176) {
    int j = t - 128;
    int a = j / 6, r = j % 6, m = r / 3, c = r % 3;
    float cnt = acnt[a];
    float v = 0.f;  // empty sector -> NaN -> nan_to_num -> 0
    if (cnt > 0.f) {
      float s1v = as1[(b * 3 + c) * 8 + a], s2v = as2[(b * 3 + c) * 8 + a];
      float mean = s1v / cnt;
      if (m == 0)
        v = mean;
      else {
        float var = (s2v - cnt * mean * mean) / fmaxf(cnt - 1.f, 1.f);
        v = sqrtf(fmaxf(var, 0.f));
      }
    }
    comb[t] = fix_nan(v, 1e4f, -1e4f);
  }
  __syncthreads();
  float h = lb1[t];
  const float* wr = lw1 + t * 176;
#pragma unroll 8
  for (int j = 0; j < 176; ++j) h = fmaf(comb[j], wr[j], h);
  red[t] = h;
  __syncthreads();
  for (int s = 128; s > 0; s >>= 1) {
    if (t < s) red[t] += red[t + s];
    __syncthreads();
  }
  if (t == 0) s_mu = red[0] * (1.0f / 256.0f);
  __syncthreads();
  float mu = s_mu;
  float d = h - mu;
  red[t] = d * d;
  __syncthreads();
  for (int s = 128; s > 0; s >>= 1) {
    if (t < s) red[t] += red[t + s];
    __syncthreads();
  }
  if (t == 0) s_var = red[0] * (1.0f / 256.0f);
  __syncthreads();
  float hn = d / sqrtf(s_var + 1e-5f) * lng[t] + lnb[t];
  hrelu[t] = fmaxf(hn, 0.f);
  __syncthreads();
  if (t < 128) {
    float o = lb2[t];
    const float* w2r = lw2 + t * 256;
#pragma unroll 8
    for (int j = 0; j < 256; ++j) o = fmaf(hrelu[j], w2r[j], o);
    o = fminf(fmaxf(o, -100.f), 100.f);
    out[b * 128 + t] = fix_nan(o, 100.f, -100.f);
  }
}

// ---------------- host launcher ----------------
extern "C" void kernel_launch(void* const* d_in, const int* in_sizes, int n_in,
                              void* d_out, int out_size, void* d_ws, size_t ws_size,
                              hipStream_t stream) {
  const float* x    = (const float*)d_in[0];
  const float* mw1  = (const float*)d_in[1];
  const float* mb1  = (const float*)d_in[2];
  const float* mbn1 = (const float*)d_in[3];
  const float* mw2  = (const float*)d_in[4];
  const float* mb2  = (const float*)d_in[5];
  const float* mbn2 = (const float*)d_in[6];
  const float* pw1  = (const float*)d_in[7];
  const float* pb1  = (const float*)d_in[8];
  const float* pbn1 = (const float*)d_in[9];
  const float* pw2  = (const float*)d_in[10];
  const float* pb2  = (const float*)d_in[11];
  const float* pbn2 = (const float*)d_in[12];
  const float* rw1  = (const float*)d_in[13];
  const float* rb1  = (const float*)d_in[14];
  const float* rbn1 = (const float*)d_in[15];
  const float* rw2  = (const float*)d_in[16];
  const float* rb2  = (const float*)d_in[17];
  const float* rbn2 = (const float*)d_in[18];
  const float* lw1  = (const float*)d_in[19];
  const float* lb1  = (const float*)d_in[20];
  const float* lng  = (const float*)d_in[21];
  const float* lnb  = (const float*)d_in[22];
  const float* lw2  = (const float*)d_in[23];
  const float* lb2  = (const float*)d_in[24];

  float* ws = (float*)d_ws;
  float* out = (float*)d_out;

  float* fc    = ws + OFF_FC;
  float* mlog  = ws + OFF_MLOG;
  float* phb   = ws + OFF_PH;
  float* rsum  = ws + OFF_RSUM;
  float* rcnt  = ws + OFF_RCNT;
  float* as1   = ws + OFF_AS1;
  float* as2   = ws + OFF_AS2;
  float* acnt  = ws + OFF_ACNT;
  float* mpool = ws + OFF_MPOOL;
  float* ppool = ws + OFF_PPOOL;
  float* par   = ws + OFF_PAR;
  unsigned short* wbm  = (unsigned short*)(ws + OFF_WBM);
  unsigned short* wbp  = (unsigned short*)(ws + OFF_WBP);
  unsigned short* w1bm = (unsigned short*)(ws + OFF_W1BM);
  unsigned short* w1bp = (unsigned short*)(ws + OFF_W1BP);

  row_fft_prep<<<6337, 256, 0, stream>>>(x, fc, rsum,
                                         mw1, pw1, mw2, pw2, mb1, mbn1, mb2, mbn2,
                                         pb1, pbn1, pb2, pbn2, rb1, rbn1, rb2, rbn2,
                                         par, wbm, wbp, w1bm, w1bp);
  col_fft_stats<<<dim3(129, 3, 16), 256, 0, stream>>>(fc, mlog, phb, rsum, rcnt,
                                                      as1, as2, acnt);
  conv_mfma<64><<<dim3(16, 16, 16), 256, 0, stream>>>(
      mlog, w1bm, wbm, par + 0, par + 64, par + 128, par + 192, mpool);
  conv_mfma<32><<<dim3(16, 16, 16), 256, 0, stream>>>(
      phb, w1bp, wbp, par + 256, par + 288, par + 320, par + 352, ppool);
  final_mlp<<<16, 256, 0, stream>>>(rsum, rcnt, rw1, rw2, par + 384, par + 416,
                                    par + 448, par + 480, mpool, ppool, as1, as2,
                                    acnt, lw1, lb1, lng, lnb, lw2, lb2, out);
}

// Round 6
// 460.116 us; speedup vs baseline: 4.1614x; 1.2243x over previous
//
#include <hip/hip_runtime.h>
#include <math.h>

#define PI_F 3.14159274101257324f   // float(np.pi)
#define TWO_PI_256 0.02454369260617026f   // 2*pi/256
#define TWO_PI_16  0.39269908169872414f   // 2*pi/16

typedef __attribute__((ext_vector_type(8))) short bf16x8;   // 4 VGPRs
typedef __attribute__((ext_vector_type(4))) float f32x4;

// ---------------- workspace layout (float offsets) ----------------
static const size_t OFF_FC    = 0;                    // row-FFT complex out [B*C*256][129]*2
static const size_t OFF_MLOG  = 3170304;              // [B,C,256,129]
static const size_t OFF_PH    = 4755456;              // [B,C,256,129]
static const size_t OFF_RSUM  = 9486336;              // [B,C,32]
static const size_t OFF_RCNT  = OFF_RSUM + 1536;      // [32]
static const size_t OFF_AS1   = OFF_RCNT + 32;        // [B,C,8]
static const size_t OFF_AS2   = OFF_AS1 + 384;        // [B,C,8]
static const size_t OFF_ACNT  = OFF_AS2 + 384;        // [8]
static const size_t OFF_MPOOL = OFF_ACNT + 8;         // [B,64]
static const size_t OFF_PPOOL = OFF_MPOOL + 1024;     // [B,32]
static const size_t OFF_RF    = OFF_PPOOL + 512;      // (unused)
static const size_t OFF_PAR   = OFF_RF + 512;         // 512 folded BN params
static const size_t OFF_WBM   = OFF_PAR + 512;        // mag conv2 w [9][64][64] bf16
static const size_t OFF_WBP   = OFF_WBM + 18432;      // ph conv2 w [9][32][32] bf16
static const size_t OFF_W1BM  = OFF_WBP + 4608;       // mag conv1 w [64][32] bf16
static const size_t OFF_W1BP  = OFF_W1BM + 1024;      // ph conv1 w [32][32] bf16
// param sub-offsets: sm1 0, tm1 64, sm2 128, tm2 192, sp1 256, tp1 288, sp2 320, tp2 352,
//                    sr1 384, tr1 416, sr2 448, tr2 480

__device__ __forceinline__ float fix_nan(float v, float pinf, float ninf) {
  if (isnan(v)) return 0.f;
  if (isinf(v)) return v > 0.f ? pinf : ninf;
  return v;
}

__device__ __forceinline__ unsigned short f2bf(float f) {
  unsigned u = __float_as_uint(f);
  unsigned r = (u + 0x7FFFu + ((u >> 16) & 1u)) >> 16;   // RNE (finite values only)
  return (unsigned short)r;
}

__device__ __forceinline__ void fold_bn(const float* bn, int C, int c, float cb,
                                        float* s, float* t) {
  float g = bn[c], b = bn[C + c], m = bn[2 * C + c], v = bn[3 * C + c];
  float sc = g / sqrtf(v + 1e-5f);
  *s = sc;
  *t = b + (cb - m) * sc;
}

// ---------------- row rFFT (radix-16) + fused prep + ws zeroing ----------------
// blocks 0..12287: one 256-pt row rFFT each, two-stage radix-16:
//   S[b][m] = sum_a x[16a+b] W16^{ma};  F[k] = sum_b S[b][k&15] W256^{kb}
// Twiddles by in-register complex rotation -> no scattered LDS reads.
// blocks >= 12288: weight/BN prep. Block 0 zeroes accumulators.
__global__ __launch_bounds__(256) void row_fft_prep(
    const float* __restrict__ x, float* __restrict__ Fc, float* __restrict__ zbuf,
    const float* __restrict__ mw1, const float* __restrict__ pw1,
    const float* __restrict__ mw2, const float* __restrict__ pw2,
    const float* __restrict__ mb1, const float* __restrict__ mbn1,
    const float* __restrict__ mb2, const float* __restrict__ mbn2,
    const float* __restrict__ pb1, const float* __restrict__ pbn1,
    const float* __restrict__ pb2, const float* __restrict__ pbn2,
    const float* __restrict__ rb1, const float* __restrict__ rbn1,
    const float* __restrict__ rb2, const float* __restrict__ rbn2,
    float* __restrict__ par, unsigned short* __restrict__ wbm,
    unsigned short* __restrict__ wbp, unsigned short* __restrict__ w1bm,
    unsigned short* __restrict__ w1bp) {
  const int blk = blockIdx.x;
  const int tid = threadIdx.x;
  if (blk >= 12288) {
    int idx = (blk - 12288) * 256 + tid;
    if (idx < 36864) {
      int pos = idx / 4096, rem = idx % 4096;
      int oc = rem >> 6, ci = rem & 63;
      wbm[idx] = f2bf(mw2[(oc * 64 + ci) * 9 + pos]);
    } else if (idx < 46080) {
      int i = idx - 36864;
      int pos = i / 1024, rem = i % 1024;
      int oc = rem >> 5, ci = rem & 31;
      wbp[i] = f2bf(pw2[(oc * 32 + ci) * 9 + pos]);
    } else if (idx < 46336) {
      int i = idx - 46080;  // 0..255
      float s, t;
      if (i < 64)       { fold_bn(mbn1, 64, i, mb1[i], &s, &t);          par[i] = s;       par[64 + i] = t; }
      else if (i < 128) { int c = i - 64;  fold_bn(mbn2, 64, c, mb2[c], &s, &t); par[128 + c] = s; par[192 + c] = t; }
      else if (i < 160) { int c = i - 128; fold_bn(pbn1, 32, c, pb1[c], &s, &t); par[256 + c] = s; par[288 + c] = t; }
      else if (i < 192) { int c = i - 160; fold_bn(pbn2, 32, c, pb2[c], &s, &t); par[320 + c] = s; par[352 + c] = t; }
      else if (i < 224) { int c = i - 192; fold_bn(rbn1, 32, c, rb1[c], &s, &t); par[384 + c] = s; par[416 + c] = t; }
      else              { int c = i - 224; fold_bn(rbn2, 32, c, rb2[c], &s, &t); par[448 + c] = s; par[480 + c] = t; }
    } else if (idx < 48384) {
      int i = idx - 46336;                 // conv1 mag w [oc][k], k=c*9+dy*3+dx, pad->0
      int oc = i >> 5, k = i & 31;
      w1bm[i] = (k < 27) ? f2bf(mw1[oc * 27 + k]) : (unsigned short)0;
    } else if (idx < 49408) {
      int i = idx - 48384;
      int oc = i >> 5, k = i & 31;
      w1bp[i] = (k < 27) ? f2bf(pw1[oc * 27 + k]) : (unsigned short)0;
    }
    return;
  }
  if (blk == 0) {
    for (int i = tid; i < 3880; i += 256) zbuf[i] = 0.f;   // rsum..ppool accumulators
  }
  __shared__ float xr[256];
  __shared__ float2 sS[256];
  {
    float v = x[(size_t)blk * 256 + tid];
    xr[tid] = fminf(fmaxf(v, -10.f), 10.f);
  }
  __syncthreads();
  // stage 1: real-input 16-pt DFTs over strided subsequences
  {
    int b16 = tid >> 4, m = tid & 15;
    float sW, cW;
    sincosf(TWO_PI_16 * (float)m, &sW, &cW);   // W = e^{-i 2pi m/16} = (cW, -sW)
    float sr = 0.f, si = 0.f, wr = 1.f, wi = 0.f;
#pragma unroll
    for (int a = 0; a < 16; ++a) {
      float xv = xr[a * 16 + b16];
      sr = fmaf(xv, wr, sr);
      si = fmaf(xv, wi, si);
      float nr = wr * cW + wi * sW;
      float ni = wi * cW - wr * sW;
      wr = nr; wi = ni;
    }
    sS[b16 * 16 + m] = make_float2(sr, si);
  }
  __syncthreads();
  // stage 2: combine with W256^{kb}
  if (tid < 129) {
    int m2 = tid & 15;
    float sK, cK;
    sincosf(TWO_PI_256 * (float)tid, &sK, &cK);  // e^{-i 2pi k/256} = (cK, -sK)
    float fr = 0.f, fi = 0.f, wr = 1.f, wi = 0.f;
#pragma unroll
    for (int bb = 0; bb < 16; ++bb) {
      float2 s = sS[bb * 16 + m2];
      fr = fmaf(s.x, wr, fr); fr = fmaf(-s.y, wi, fr);
      fi = fmaf(s.x, wi, fi); fi = fmaf(s.y, wr, fi);
      float nr = wr * cK + wi * sK;
      float ni = wi * cK - wr * sK;
      wr = nr; wi = ni;
    }
    float2* o = (float2*)Fc;
    o[(size_t)blk * 129 + tid] = make_float2(fr, fi);
  }
}

// ---------------- column DFT (radix-16, 3 channels/block) + stats ----------------
__global__ __launch_bounds__(256) void col_fft_stats(
    const float* __restrict__ Fc, float* __restrict__ mlog, float* __restrict__ ph,
    float* __restrict__ rsum, float* __restrict__ rcnt, float* __restrict__ as1,
    float* __restrict__ as2, float* __restrict__ acnt) {
  const int k = blockIdx.x, b = blockIdx.y;
  const int tid = threadIdx.x;
  const int cp = tid >> 7;          // 2 histogram copies
  __shared__ float2 col[3][256];
  __shared__ float2 sS[3][256];
  __shared__ float l_rs[3][2][32];
  __shared__ float l_rc[32];
  __shared__ float l_s1[3][2][8], l_s2[3][2][8];
  __shared__ float l_ac[8];
  for (int i = tid; i < 192; i += 256) {
    int c = i / 64, r = i % 64;
    l_rs[c][r >> 5][r & 31] = 0.f;
  }
  if (tid < 32) l_rc[tid] = 0.f;
  if (tid < 48) { int c = tid / 16, r = tid % 16; l_s1[c][r >> 3][r & 7] = 0.f; l_s2[c][r >> 3][r & 7] = 0.f; }
  if (tid < 8) l_ac[tid] = 0.f;
  const float2* fc = (const float2*)Fc;
#pragma unroll
  for (int c = 0; c < 3; ++c)
    col[c][tid] = fc[((size_t)((b * 3 + c) * 256) + tid) * 129 + k];
  __syncthreads();
  // stage 1 (complex input)
  {
    int b16 = tid >> 4, m = tid & 15;
    float sW, cW;
    sincosf(TWO_PI_16 * (float)m, &sW, &cW);
#pragma unroll
    for (int c = 0; c < 3; ++c) {
      float sr = 0.f, si = 0.f, wr = 1.f, wi = 0.f;
#pragma unroll
      for (int a = 0; a < 16; ++a) {
        float2 v = col[c][a * 16 + b16];
        sr = fmaf(v.x, wr, sr); sr = fmaf(-v.y, wi, sr);
        si = fmaf(v.x, wi, si); si = fmaf(v.y, wr, si);
        float nr = wr * cW + wi * sW;
        float ni = wi * cW - wr * sW;
        wr = nr; wi = ni;
      }
      sS[c][b16 * 16 + m] = make_float2(sr, si);
    }
  }
  __syncthreads();
  const int j = tid;
  float sK, cK;
  sincosf(TWO_PI_256 * (float)j, &sK, &cK);
  float gr[3], gi[3];
#pragma unroll
  for (int c = 0; c < 3; ++c) {
    float fr = 0.f, fi = 0.f, wr = 1.f, wi = 0.f;
#pragma unroll
    for (int bb = 0; bb < 16; ++bb) {
      float2 s = sS[c][bb * 16 + (j & 15)];
      fr = fmaf(s.x, wr, fr); fr = fmaf(-s.y, wi, fr);
      fi = fmaf(s.x, wi, fi); fi = fmaf(s.y, wr, fi);
      float nr = wr * cK + wi * sK;
      float ni = wi * cK - wr * sK;
      wr = nr; wi = ni;
    }
    gr[c] = fr; gi[c] = fi;
  }
  // bins once per (j,k) (bit-exact fp32 replication of reference index math)
  float fy = (float)(j < 128 ? j : j - 256) * (1.0f / 256.0f);
  float fx = (float)k * (1.0f / 256.0f);
  float rad = sqrtf(fx * fx + fy * fy);
  float denom = sqrtf(0.5f) + 1e-8f;
  int rb = (int)((rad / denom) * 31.0f);
  rb = rb < 0 ? 0 : (rb > 31 ? 31 : rb);
  float ang = atan2f(fy, fx + 1e-8f);
  int ab = (int)((ang + PI_F) / (2.0f * PI_F) * 8.0f);
  ab = ab < 0 ? 0 : (ab > 7 ? 7 : ab);
#pragma unroll
  for (int c = 0; c < 3; ++c) {
    float mag = sqrtf(gr[c] * gr[c] + gi[c] * gi[c]);
    mag = fminf(fmaxf(mag, 1e-8f), 1e6f);
    float ml = fminf(fmaxf(log1pf(mag), -20.f), 20.f);
    float p = fminf(fmaxf(atan2f(gi[c], gr[c]) / PI_F, -1.f), 1.f);
    size_t oidx = ((size_t)((b * 3 + c) * 256) + j) * 129 + k;
    mlog[oidx] = ml;
    ph[oidx] = p;
    atomicAdd(&l_rs[c][cp][rb], mag);
    atomicAdd(&l_s1[c][cp][ab], mag);
    atomicAdd(&l_s2[c][cp][ab], mag * mag);
  }
  if (b == 0) {
    atomicAdd(&l_rc[rb], 1.0f);
    atomicAdd(&l_ac[ab], 1.0f);
  }
  __syncthreads();
  if (tid < 96) {
    int c = tid / 32, i2 = tid % 32;
    atomicAdd(&rsum[(b * 3 + c) * 32 + i2], l_rs[c][0][i2] + l_rs[c][1][i2]);
  } else if (tid < 120) {
    int t2 = tid - 96;
    int c = t2 / 8, a2 = t2 % 8;
    atomicAdd(&as1[(b * 3 + c) * 8 + a2], l_s1[c][0][a2] + l_s1[c][1][a2]);
    atomicAdd(&as2[(b * 3 + c) * 8 + a2], l_s2[c][0][a2] + l_s2[c][1][a2]);
  }
  if (b == 0) {
    if (tid < 32) atomicAdd(&rcnt[tid], l_rc[tid]);
    else if (tid < 40) atomicAdd(&acnt[tid - 32], l_ac[tid - 32]);
  }
}

// ---------------- fused upsample -> conv1(MFMA) -> conv2(MFMA) -> pool ----------------
// 16x16 tile, 4 waves, K-SPLIT: f1 holds 32 channels at a time ([324][40] bf16,
// LDS ~31 KB -> 3+ blocks/CU). Per half: conv1 (32 oc) -> sync -> conv2 (32 ci).
// B-fragments JIT-loaded per (kx) granule; BN/weight frags reloaded per half.
template <int C2>
__global__ __launch_bounds__(256, (C2 == 64 ? 3 : 4)) void conv_mfma(
    const float* __restrict__ src,           // [B,3,256,129] spectral plane
    const unsigned short* __restrict__ w1b,  // [C2][32] bf16 conv1 weights
    const unsigned short* __restrict__ wB,   // [9][C2][C2] bf16 conv2 [pos][oc][ci]
    const float* __restrict__ s1, const float* __restrict__ t1,
    const float* __restrict__ s2, const float* __restrict__ t2,
    float* __restrict__ pool) {
  constexpr int HALVES = C2 / 32;
  constexpr int ST = 40;                     // 32 ci + 8 pad (rows 80 B, 16B-aligned)
  constexpr int WNT = C2 / 32;               // oc tiles per wave (2 or 1)

  __shared__ float s_in[3][20][20];
  __shared__ float s_sc1[C2], s_sh1[C2];
  __shared__ __align__(16) unsigned short s_f1[324 * ST];

  const int tid = threadIdx.x;
  const int b = blockIdx.z;
  const int tx0 = blockIdx.x * 16, ty0 = blockIdx.y * 16;
  const int lane = tid & 63, wv = tid >> 6;
  const int ln = lane & 15, q = lane >> 4;
  const int ntg = wv & 1, half_w = wv >> 1;
  const int ocb0 = ntg * WNT * 16;

  // stage input tile (halo 2) with fused bilinear W-upsample (129 -> 256)
  for (int idx = tid; idx < 1200; idx += 256) {
    int c = idx / 400, r = idx % 400, iy = r / 20, ix = r % 20;
    int gy = ty0 - 2 + iy, gx = tx0 - 2 + ix;
    float v = 0.f;
    if ((unsigned)gy < 256u && (unsigned)gx < 256u) {
      float srcx = ((float)gx + 0.5f) * (129.0f / 256.0f) - 0.5f;
      float fl = floorf(srcx);
      float w = srcx - fl;
      int x0 = (int)fl, x1 = x0 + 1;
      x0 = x0 < 0 ? 0 : x0;
      x1 = x1 > 128 ? 128 : x1;
      const float* rowp = src + ((size_t)(b * 3 + c) * 256 + gy) * 129;
      v = rowp[x0] * (1.f - w) + rowp[x1] * w;
    }
    s_in[c][iy][ix] = v;
  }
  if (tid < C2) { s_sc1[tid] = s1[tid]; s_sh1[tid] = t1[tid]; }
  __syncthreads();

  // per-lane conv1 gather offsets (k = c*9 + dy*3 + dx)
  const float* sp = &s_in[0][0][0];
  int koff[8];
#pragma unroll
  for (int j = 0; j < 8; ++j) {
    int k = q * 8 + j;
    if (k < 27) {
      int c = k / 9, rr = k - c * 9, dy = rr / 3, dx = rr - dy * 3;
      koff[j] = (c * 20 + dy) * 20 + dx;
    } else koff[j] = -1;
  }

  f32x4 acc[WNT][8];
#pragma unroll
  for (int w = 0; w < WNT; ++w)
#pragma unroll
    for (int i = 0; i < 8; ++i)
      acc[w][i] = (f32x4){0.f, 0.f, 0.f, 0.f};

  const int rbase = half_w * 8;

  for (int hf = 0; hf < HALVES; ++hf) {
    if (hf > 0) __syncthreads();   // conv2(hf-1) readers done before overwrite
    // conv1 weights + BN params for this half's 32 oc (short live ranges)
    bf16x8 b1h[2];
    float c1sc[2][4], c1sh[2][4];
#pragma unroll
    for (int w = 0; w < 2; ++w) {
      int nt = hf * 2 + w;
      b1h[w] = *(const bf16x8*)&w1b[(nt * 16 + ln) * 32 + q * 8];
#pragma unroll
      for (int r = 0; r < 4; ++r) {
        c1sc[w][r] = s_sc1[hf * 32 + w * 16 + q * 4 + r];
        c1sh[w][r] = s_sh1[hf * 32 + w * 16 + q * 4 + r];
      }
    }
    // ---- conv1: D[oc][pixel], 21 pixel-tiles of 16 over the 18x18 halo ----
    for (int mt = wv; mt < 21; mt += 4) {
      int p = mt * 16 + ln;
      int pc = p < 324 ? p : 0;
      int py = pc / 18, px = pc - py * 18;
      int pix = py * 20 + px;
      union { bf16x8 v; unsigned u[4]; } af;
#pragma unroll
      for (int jj = 0; jj < 4; ++jj) {
        float v0 = (koff[2 * jj] >= 0) ? sp[koff[2 * jj] + pix] : 0.f;
        float v1 = (koff[2 * jj + 1] >= 0) ? sp[koff[2 * jj + 1] + pix] : 0.f;
        af.u[jj] = (unsigned)f2bf(v0) | ((unsigned)f2bf(v1) << 16);
      }
      bool inim = false;
      if (p < 324) {
        int gy = ty0 - 1 + py, gx = tx0 - 1 + px;
        inim = ((unsigned)gy < 256u) && ((unsigned)gx < 256u);
      }
#pragma unroll
      for (int w = 0; w < 2; ++w) {
        f32x4 c1 = __builtin_amdgcn_mfma_f32_16x16x32_bf16(
            b1h[w], af.v, (f32x4){0.f, 0.f, 0.f, 0.f}, 0, 0, 0);
        if (p < 324) {
          float v0 = inim ? fmaxf(fmaf(c1[0], c1sc[w][0], c1sh[w][0]), 0.f) : 0.f;
          float v1 = inim ? fmaxf(fmaf(c1[1], c1sc[w][1], c1sh[w][1]), 0.f) : 0.f;
          float v2 = inim ? fmaxf(fmaf(c1[2], c1sc[w][2], c1sh[w][2]), 0.f) : 0.f;
          float v3 = inim ? fmaxf(fmaf(c1[3], c1sc[w][3], c1sh[w][3]), 0.f) : 0.f;
          uint2 pk;
          pk.x = (unsigned)f2bf(v0) | ((unsigned)f2bf(v1) << 16);
          pk.y = (unsigned)f2bf(v2) | ((unsigned)f2bf(v3) << 16);
          *(uint2*)&s_f1[p * ST + w * 16 + q * 4] = pk;
        }
      }
    }
    __syncthreads();
    // ---- conv2: 3 kx granules over this half's 32 ci ----
#pragma unroll
    for (int kx = 0; kx < 3; ++kx) {
      bf16x8 Bf[WNT * 3];
#pragma unroll
      for (int w = 0; w < WNT; ++w)
#pragma unroll
        for (int ky = 0; ky < 3; ++ky)
          Bf[w * 3 + ky] = *(const bf16x8*)&wB[((size_t)(ky * 3 + kx) * C2 + ocb0 + w * 16 + ln) * C2 +
                                               hf * 32 + q * 8];
      bf16x8 a[10];
#pragma unroll
      for (int rr = 0; rr < 10; ++rr)
        a[rr] = *(const bf16x8*)&s_f1[((rbase + rr) * 18 + ln + kx) * ST + q * 8];
#pragma unroll
      for (int ky = 0; ky < 3; ++ky)
#pragma unroll
        for (int w = 0; w < WNT; ++w)
#pragma unroll
          for (int i = 0; i < 8; ++i)
            acc[w][i] = __builtin_amdgcn_mfma_f32_16x16x32_bf16(a[i + ky], Bf[w * 3 + ky],
                                                                acc[w][i], 0, 0, 0);
    }
  }

  // epilogue: BN+ReLU + pool partial. D: col(ln)=oc, rows=pixel cols (q*4+r).
#pragma unroll
  for (int w = 0; w < WNT; ++w) {
    const int oc = ocb0 + w * 16 + ln;
    const float sc = s2[oc], sh = t2[oc];
    float v = 0.f;
#pragma unroll
    for (int i = 0; i < 8; ++i)
#pragma unroll
      for (int r = 0; r < 4; ++r)
        v += fmaxf(fmaf(acc[w][i][r], sc, sh), 0.f);
    v += __shfl_xor(v, 16);
    v += __shfl_xor(v, 32);
    if (q == 0) atomicAdd(&pool[b * C2 + oc], v);
  }
}

// ---------------- final: radial conv branch + comb + linear/LN/relu/linear ----------------
__global__ __launch_bounds__(256) void final_mlp(
    const float* __restrict__ rsum, const float* __restrict__ rcnt,
    const float* __restrict__ rw1, const float* __restrict__ rw2,
    const float* __restrict__ sr1, const float* __restrict__ tr1,
    const float* __restrict__ sr2, const float* __restrict__ tr2,
    const float* __restrict__ mpool, const float* __restrict__ ppool,
    const float* __restrict__ as1, const float* __restrict__ as2,
    const float* __restrict__ acnt,
    const float* __restrict__ lw1, const float* __restrict__ lb1,
    const float* __restrict__ lng, const float* __restrict__ lnb,
    const float* __restrict__ lw2, const float* __restrict__ lb2,
    float* __restrict__ out) {
  int b = blockIdx.x, t = threadIdx.x;
  __shared__ float rad[3][32];
  __shared__ float rf1[32][32];
  __shared__ float rf2[32][32];
  __shared__ float rfv[32];
  __shared__ float comb[176];
  __shared__ float red[256];
  __shared__ float hrelu[256];
  __shared__ float s_mu, s_var;

  if (t < 96) {
    int c = t / 32, i = t % 32;
    float cnt = fmaxf(rcnt[i], 1.0f);
    float v = rsum[(b * 3 + c) * 32 + i] / cnt;
    rad[c][i] = fminf(fmaxf(v, 0.f), 1e6f);
  }
  __syncthreads();
  for (int idx = t; idx < 1024; idx += 256) {
    int oc = idx >> 5, i = idx & 31;
    float a = 0.f;
    for (int c = 0; c < 3; ++c)
#pragma unroll
      for (int d = 0; d < 3; ++d) {
        int ii = i + d - 1;
        if (ii >= 0 && ii < 32) a = fmaf(rad[c][ii], rw1[(oc * 3 + c) * 3 + d], a);
      }
    rf1[oc][i] = fmaxf(fmaf(a, sr1[oc], tr1[oc]), 0.f);
  }
  __syncthreads();
  for (int idx = t; idx < 1024; idx += 256) {
    int oc = idx >> 5, i = idx & 31;
    float a = 0.f;
    for (int c = 0; c < 32; ++c)
#pragma unroll
      for (int d = 0; d < 3; ++d) {
        int ii = i + d - 1;
        if (ii >= 0 && ii < 32) a = fmaf(rf1[c][ii], rw2[(oc * 32 + c) * 3 + d], a);
      }
    rf2[oc][i] = fmaxf(fmaf(a, sr2[oc], tr2[oc]), 0.f);
  }
  __syncthreads();
  if (t < 32) {
    float s = 0.f;
    for (int i = 0; i < 32; ++i) s += rf2[t][i];
    rfv[t] = s * (1.0f / 32.0f);
  }
  __syncthreads();

  if (t < 64) comb[t] = fix_nan(mpool[b * 64 + t] * (1.0f / 65536.0f), 1e4f, -1e4f);
  else if (t < 96) comb[t] = fix_nan(ppool[b * 32 + t - 64] * (1.0f / 65536.0f), 1e4f, -1e4f);
  else if (t < 128) comb[t] = fix_nan(rfv[t - 96], 1e4f, -1e4f);
  else if (t < 176) {
    int j = t - 128;
    int a = j / 6, r = j % 6, m = r / 3, c = r % 3;
    float cnt = acnt[a];
    float v = 0.f;  // empty sector -> NaN -> nan_to_num -> 0
    if (cnt > 0.f) {
      float s1v = as1[(b * 3 + c) * 8 + a], s2v = as2[(b * 3 + c) * 8 + a];
      float mean = s1v / cnt;
      if (m == 0)
        v = mean;
      else {
        float var = (s2v - cnt * mean * mean) / fmaxf(cnt - 1.f, 1.f);
        v = sqrtf(fmaxf(var, 0.f));
      }
    }
    comb[t] = fix_nan(v, 1e4f, -1e4f);
  }
  __syncthreads();
  float h = lb1[t];
  const float* wr = lw1 + t * 176;
#pragma unroll 8
  for (int j = 0; j < 176; ++j) h = fmaf(comb[j], wr[j], h);
  red[t] = h;
  __syncthreads();
  for (int s = 128; s > 0; s >>= 1) {
    if (t < s) red[t] += red[t + s];
    __syncthreads();
  }
  if (t == 0) s_mu = red[0] * (1.0f / 256.0f);
  __syncthreads();
  float mu = s_mu;
  float d = h - mu;
  red[t] = d * d;
  __syncthreads();
  for (int s = 128; s > 0; s >>= 1) {
    if (t < s) red[t] += red[t + s];
    __syncthreads();
  }
  if (t == 0) s_var = red[0] * (1.0f / 256.0f);
  __syncthreads();
  float hn = d / sqrtf(s_var + 1e-5f) * lng[t] + lnb[t];
  hrelu[t] = fmaxf(hn, 0.f);
  __syncthreads();
  if (t < 128) {
    float o = lb2[t];
    const float* w2r = lw2 + t * 256;
#pragma unroll 8
    for (int j = 0; j < 256; ++j) o = fmaf(hrelu[j], w2r[j], o);
    o = fminf(fmaxf(o, -100.f), 100.f);
    out[b * 128 + t] = fix_nan(o, 100.f, -100.f);
  }
}

// ---------------- host launcher ----------------
extern "C" void kernel_launch(void* const* d_in, const int* in_sizes, int n_in,
                              void* d_out, int out_size, void* d_ws, size_t ws_size,
                              hipStream_t stream) {
  const float* x    = (const float*)d_in[0];
  const float* mw1  = (const float*)d_in[1];
  const float* mb1  = (const float*)d_in[2];
  const float* mbn1 = (const float*)d_in[3];
  const float* mw2  = (const float*)d_in[4];
  const float* mb2  = (const float*)d_in[5];
  const float* mbn2 = (const float*)d_in[6];
  const float* pw1  = (const float*)d_in[7];
  const float* pb1  = (const float*)d_in[8];
  const float* pbn1 = (const float*)d_in[9];
  const float* pw2  = (const float*)d_in[10];
  const float* pb2  = (const float*)d_in[11];
  const float* pbn2 = (const float*)d_in[12];
  const float* rw1  = (const float*)d_in[13];
  const float* rb1  = (const float*)d_in[14];
  const float* rbn1 = (const float*)d_in[15];
  const float* rw2  = (const float*)d_in[16];
  const float* rb2  = (const float*)d_in[17];
  const float* rbn2 = (const float*)d_in[18];
  const float* lw1  = (const float*)d_in[19];
  const float* lb1  = (const float*)d_in[20];
  const float* lng  = (const float*)d_in[21];
  const float* lnb  = (const float*)d_in[22];
  const float* lw2  = (const float*)d_in[23];
  const float* lb2  = (const float*)d_in[24];

  float* ws = (float*)d_ws;
  float* out = (float*)d_out;

  float* fc    = ws + OFF_FC;
  float* mlog  = ws + OFF_MLOG;
  float* phb   = ws + OFF_PH;
  float* rsum  = ws + OFF_RSUM;
  float* rcnt  = ws + OFF_RCNT;
  float* as1   = ws + OFF_AS1;
  float* as2   = ws + OFF_AS2;
  float* acnt  = ws + OFF_ACNT;
  float* mpool = ws + OFF_MPOOL;
  float* ppool = ws + OFF_PPOOL;
  float* par   = ws + OFF_PAR;
  unsigned short* wbm  = (unsigned short*)(ws + OFF_WBM);
  unsigned short* wbp  = (unsigned short*)(ws + OFF_WBP);
  unsigned short* w1bm = (unsigned short*)(ws + OFF_W1BM);
  unsigned short* w1bp = (unsigned short*)(ws + OFF_W1BP);

  row_fft_prep<<<12481, 256, 0, stream>>>(x, fc, rsum,
                                          mw1, pw1, mw2, pw2, mb1, mbn1, mb2, mbn2,
                                          pb1, pbn1, pb2, pbn2, rb1, rbn1, rb2, rbn2,
                                          par, wbm, wbp, w1bm, w1bp);
  col_fft_stats<<<dim3(129, 16), 256, 0, stream>>>(fc, mlog, phb, rsum, rcnt,
                                                   as1, as2, acnt);
  conv_mfma<64><<<dim3(16, 16, 16), 256, 0, stream>>>(
      mlog, w1bm, wbm, par + 0, par + 64, par + 128, par + 192, mpool);
  conv_mfma<32><<<dim3(16, 16, 16), 256, 0, stream>>>(
      phb, w1bp, wbp, par + 256, par + 288, par + 320, par + 352, ppool);
  final_mlp<<<16, 256, 0, stream>>>(rsum, rcnt, rw1, rw2, par + 384, par + 416,
                                    par + 448, par + 480, mpool, ppool, as1, as2,
                                    acnt, lw1, lb1, lng, lnb, lw2, lb2, out);
}